// Round 17
// baseline (282.728 us; speedup 1.0000x reference)
//
#include <hip/hip_runtime.h>
#include <math.h>

// ---------------------------------------------------------------------------
// InteractionBlock: gather -> per-edge tensor-product -> scatter -> linear
// N=50000 nodes, E=800000 edges, MUL=32.
//
// Round-16: skip-connection moved out of node_final.
//  * node_prep computes sc_s/sc_v with f32 Wsc in LDS (44KB, 3 blk/CU, zero
//    unpacks — nf row already staged there) and writes out = skip.
//  * node_final = linear only: wqb 8KB + svtp 20KB = 28KB -> 5 blk/CU;
//    2 nodes share each weight unpack in one u-loop (23 -> ~6 VALU/node/iter,
//    the R15 postmortem's diagnosed issue-bound cost); epilogue out += lin.
//  * reduce (1 wave/node), scatter_build (32B records) unchanged.
//
// ws layout (float units):
//   sv1[N*64] | SVb[N*128] | recb[E*8] | cnt[N] | rs[N] | bsum[64] | boff[64]
//   (~64.4 MB)
// ---------------------------------------------------------------------------

typedef float  v2f __attribute__((ext_vector_type(2)));
typedef float  v4f __attribute__((ext_vector_type(4)));

__device__ __forceinline__ unsigned short f2bf(float x) {
    unsigned u = __float_as_uint(x);
    u += 0x7FFFu + ((u >> 16) & 1u);   // RNE
    return (unsigned short)(u >> 16);
}
__device__ __forceinline__ float bf2f(unsigned short h) {
    return __uint_as_float(((unsigned)h) << 16);
}
__device__ __forceinline__ unsigned pack_bf(float lo, float hi) {
    unsigned ul = __float_as_uint(lo);
    ul = (ul + (0x7FFFu + ((ul >> 16) & 1u))) >> 16;
    unsigned uh = __float_as_uint(hi);
    uh = (uh + (0x7FFFu + ((uh >> 16) & 1u))) & 0xFFFF0000u;
    return ul | uh;
}
__device__ __forceinline__ float bf_lo(unsigned p) { return __uint_as_float(p << 16); }
__device__ __forceinline__ float bf_hi(unsigned p) { return __uint_as_float(p & 0xFFFF0000u); }

// node_prep: W1 linear (sv1, bf16) + histogram + SKIP connection -> out
__global__ __launch_bounds__(256) void node_prep(
    const float* __restrict__ nf, const float* __restrict__ W1_s,
    const float* __restrict__ W1_v, const float* __restrict__ nattr,
    const float* __restrict__ Wsc_s, const float* __restrict__ Wsc_v,
    const int* __restrict__ eidx, int* __restrict__ cnt,
    ushort* __restrict__ sv1, float* __restrict__ out, int N, int E)
{
    __shared__ float w1s[1024];      // 4 KB
    __shared__ float w1v[1024];      // 4 KB
    __shared__ v2f ws_s01[1024];     // 8 KB  {Wsc_s[u][0][w], Wsc_s[u][1][w]}
    __shared__ v2f ws_s23[1024];     // 8 KB
    __shared__ v2f ws_v01[1024];     // 8 KB
    __shared__ v2f ws_v23[1024];     // 8 KB
    __shared__ float nrow[8][128];   // 4 KB  -> 44 KB total, 3 blk/CU

    // folded histogram of dst
    for (long long e = (long long)blockIdx.x * 256 + threadIdx.x; e < E;
         e += (long long)gridDim.x * 256)
        atomicAdd(cnt + eidx[(int)e], 1);

    int g = threadIdx.x >> 5;
    int w = threadIdx.x & 31;
    int n = blockIdx.x * 8 + g;

    for (int i = threadIdx.x; i < 1024; i += 256) {
        w1s[i] = W1_s[i];
        w1v[i] = W1_v[i];
        int uu = i >> 5, ww = i & 31;
        const float* ps = Wsc_s + (size_t)uu * 128 + ww;
        const float* pv = Wsc_v + (size_t)uu * 128 + ww;
        ws_s01[i] = (v2f){ps[0],  ps[32]};
        ws_s23[i] = (v2f){ps[64], ps[96]};
        ws_v01[i] = (v2f){pv[0],  pv[32]};
        ws_v23[i] = (v2f){pv[64], pv[96]};
    }
    if (n < N) {
        float4 q = *(const float4*)(nf + (size_t)n * 128 + w * 4);
        *(float4*)&nrow[g][w * 4] = q;
    }
    __syncthreads();
    if (n >= N) return;

    const float l1 = 0.17677669529663687f;      // 1/sqrt(32)
    const float sc_norm = 0.08838834764831843f; // 1/sqrt(128)
    v2f at01 = (v2f){nattr[(size_t)n * 4 + 0], nattr[(size_t)n * 4 + 1]};
    v2f at23 = (v2f){nattr[(size_t)n * 4 + 2], nattr[(size_t)n * 4 + 3]};

    const float* r = nrow[g];
    float ss = 0.f, vx = 0.f, vy = 0.f, vz = 0.f;
    float scs = 0.f, scv0 = 0.f, scv1 = 0.f, scv2 = 0.f;
#pragma unroll 8
    for (int u = 0; u < 32; ++u) {
        int idx = u * 32 + w;
        float ru = r[u];
        float rx = r[32 + u * 3 + 0];
        float ry = r[32 + u * 3 + 1];
        float rz = r[32 + u * 3 + 2];
        float wsv = w1v[idx];
        ss += ru * w1s[idx];
        vx += rx * wsv;
        vy += ry * wsv;
        vz += rz * wsv;
        v2f ts = at01 * ws_s01[idx] + at23 * ws_s23[idx];
        v2f tv = at01 * ws_v01[idx] + at23 * ws_v23[idx];
        float cs = ts.x + ts.y;
        float cv = tv.x + tv.y;
        scs  += ru * cs;
        scv0 += rx * cv;
        scv1 += ry * cv;
        scv2 += rz * cv;
    }
    ushort4 o;
    o.x = f2bf(ss * l1); o.y = f2bf(vx * l1);
    o.z = f2bf(vy * l1); o.w = f2bf(vz * l1);
    *(ushort4*)(sv1 + (size_t)n * 128 + w * 4) = o;

    float* orow = out + (size_t)n * 128;
    orow[w]              = scs  * sc_norm;
    orow[32 + w * 3 + 0] = scv0 * sc_norm;
    orow[32 + w * 3 + 1] = scv1 * sc_norm;
    orow[32 + w * 3 + 2] = scv2 * sc_norm;
}

// ---------------- CSR build ----------------

__global__ __launch_bounds__(1024) void scan_a(
    const int* __restrict__ cnt, int* __restrict__ rs,
    int* __restrict__ bsum, int N)
{
    int i = blockIdx.x * 1024 + threadIdx.x;
    int lane = threadIdx.x & 63;
    int wid = threadIdx.x >> 6;
    int v = (i < N) ? cnt[i] : 0;
    int incl = v;
#pragma unroll
    for (int d = 1; d < 64; d <<= 1) {
        int t = __shfl_up(incl, d);
        if (lane >= d) incl += t;
    }
    __shared__ int wtot[16];
    __shared__ int woff[16];
    if (lane == 63) wtot[wid] = incl;
    __syncthreads();
    if (wid == 0) {
        int t = (lane < 16) ? wtot[lane] : 0;
        int s = t;
#pragma unroll
        for (int d = 1; d < 16; d <<= 1) {
            int q = __shfl_up(s, d);
            if (lane >= d) s += q;
        }
        if (lane < 16) woff[lane] = s - t;
        if (lane == 15) bsum[blockIdx.x] = s;
    }
    __syncthreads();
    if (i < N) rs[i] = woff[wid] + incl - v;   // block-local exclusive prefix
}

__global__ __launch_bounds__(64) void scan_b(
    const int* __restrict__ bsum, int* __restrict__ boff, int nb)
{
    int lane = threadIdx.x;
    int carry = 0;
    for (int base = 0; base < nb; base += 64) {
        int i = base + lane;
        int v = (i < nb) ? bsum[i] : 0;
        int s = v;
#pragma unroll
        for (int d = 1; d < 64; d <<= 1) {
            int t = __shfl_up(s, d);
            if (lane >= d) s += t;
        }
        if (i < nb) boff[i] = carry + s - v;
        carry += __shfl(s, 63);
    }
}

// fused scatter + edge-MLP: sequential reads; ONE 32B record per edge at the
// dst-sorted position (2 adjacent b128 stores -> 1 cache line touched).
__global__ __launch_bounds__(256) void scatter_build(
    const float* __restrict__ ea, const float* __restrict__ ee,
    const float* __restrict__ fc1, const int* __restrict__ eidx,
    int* __restrict__ rs, const int* __restrict__ boff,
    unsigned* __restrict__ recb, int E)
{
    int e = blockIdx.x * 256 + threadIdx.x;
    if (e >= E) return;
    const float rs8 = 0.35355339059327373f;   // 1/sqrt(8)

    int d = eidx[e];
    int src = eidx[E + e];
    int p = atomicAdd(rs + d, 1) + boff[d >> 10];

    const float* eep = ee + (size_t)e * 8;
    v4f e0 = *(const v4f*)eep;
    v4f e1 = *(const v4f*)(eep + 4);
    float ev[8] = {e0.x, e0.y, e0.z, e0.w, e1.x, e1.y, e1.z, e1.w};
    float hh[8];
#pragma unroll
    for (int k = 0; k < 8; ++k) {
        float t = 0.f;
#pragma unroll
        for (int i = 0; i < 8; ++i) t += ev[i] * fc1[i * 8 + k];
        t *= rs8;
        hh[k] = t * __builtin_amdgcn_rcpf(1.f + __expf(-t)) * rs8; // silu, rs8 folded
    }
    uint4 hp;
    hp.x = pack_bf(hh[0], hh[1]);
    hp.y = pack_bf(hh[2], hh[3]);
    hp.z = pack_bf(hh[4], hh[5]);
    hp.w = pack_bf(hh[6], hh[7]);
    v4f a = *(const v4f*)(ea + (size_t)e * 4);
    uint4 t2;
    t2.x = pack_bf(a.x, a.y);
    t2.y = pack_bf(a.z, a.w);
    t2.z = (unsigned)src;
    t2.w = 0u;
    unsigned* rp = recb + (size_t)p * 8;
    *(uint4*)rp       = hp;
    *(uint4*)(rp + 4) = t2;
}

// ---------------- per-node reduction (no atomics, 1 wave = 1 node) --------

__global__ __launch_bounds__(64) void reduce_kernel(
    const float* __restrict__ fc2, const ushort* __restrict__ sv1,
    const unsigned* __restrict__ recb, const int* __restrict__ rs_end,
    const int* __restrict__ boff, const int* __restrict__ cnt,
    ushort* __restrict__ SVb, int N)
{
    __shared__ float rec[64][20];   // 5.1 KB -> wave-granular scheduling

    int l = threadIdx.x;
    int h = l >> 5;
    int u = l & 31;
    int n = blockIdx.x;

    const float inv_sqrt3 = 0.5773502691896258f;

    v2f f01[8], f23[8];
#pragma unroll
    for (int k = 0; k < 8; ++k) {
        f01[k].x = fc2[k * 128 + u];
        f01[k].y = fc2[k * 128 + 32 + u];
        f23[k].x = fc2[k * 128 + 64 + u];
        f23[k].y = fc2[k * 128 + 96 + u];
    }

    int count = cnt[n];
    int start = rs_end[n] + boff[n >> 10] - count;

    float aS0 = 0.f, aS1 = 0.f;
    float aV0x = 0.f, aV0y = 0.f, aV0z = 0.f;
    float aV1x = 0.f, aV1y = 0.f, aV1z = 0.f;

    for (int j0 = 0; j0 < count; j0 += 64) {
        int nk = count - j0; if (nk > 64) nk = 64;
        // phase 1: coalesced 32B record load + unpack (MLP precomputed)
        if (l < nk) {
            const unsigned* rp = recb + (size_t)(start + j0 + l) * 8;
            uint4 hq = *(const uint4*)rp;
            uint4 aq = *(const uint4*)(rp + 4);
            float* rr = &rec[l][0];
            *(v4f*)rr       = (v4f){bf_lo(hq.x), bf_hi(hq.x), bf_lo(hq.y), bf_hi(hq.y)};
            *(v4f*)(rr + 4) = (v4f){bf_lo(hq.z), bf_hi(hq.z), bf_lo(hq.w), bf_hi(hq.w)};
            *(v4f*)(rr + 8) = (v4f){bf_lo(aq.x), bf_hi(aq.x), bf_lo(aq.y), bf_hi(aq.y)};
            rr[12] = __uint_as_float(aq.z);
        }
        // phase 2: 2 edges/iteration (h picks the edge), branchless 1-deep
        // sv1-row prefetch.
        int pairs = (nk + 1) >> 1;
        int last = nk - 1;
        int s0 = __float_as_int(rec[h <= last ? h : last][12]);
        ushort4 q = *(const ushort4*)(sv1 + (size_t)s0 * 128 + u * 4);
        for (int jj = 0; jj < pairs; ++jj) {
            int slot = jj * 2 + h;
            int nslot = slot + 2 <= last ? slot + 2 : last;
            int sN = __float_as_int(rec[nslot][12]);
            ushort4 qn = *(const ushort4*)(sv1 + (size_t)sN * 128 + u * 4);

            float msk = (slot <= last) ? 1.f : 0.f;
            int slotc = slot <= last ? slot : last;
            const float* rr = &rec[slotc][0];
            v4f H0 = *(const v4f*)rr;
            v4f H1 = *(const v4f*)(rr + 4);
            v4f A  = *(const v4f*)(rr + 8);
            float ss = bf2f(q.x) * msk;
            float vx = bf2f(q.y), vy = bf2f(q.z), vz = bf2f(q.w);

            v2f w01 = H0.x * f01[0] + H0.y * f01[1] + H0.z * f01[2] + H0.w * f01[3]
                    + H1.x * f01[4] + H1.y * f01[5] + H1.z * f01[6] + H1.w * f01[7];
            v2f w23 = H0.x * f23[0] + H0.y * f23[1] + H0.z * f23[2] + H0.w * f23[3]
                    + H1.x * f23[4] + H1.y * f23[5] + H1.z * f23[6] + H1.w * f23[7];

            float dv = (vx * A.y + vy * A.z + vz * A.w) * msk;
            aS0 += w01.x * (ss * A.x);
            aS1 += w23.y * dv;
            float c1 = w01.y * ss;
            aV0x += c1 * A.y; aV0y += c1 * A.z; aV0z += c1 * A.w;
            float c2 = w23.x * A.x * msk;
            aV1x += c2 * vx; aV1y += c2 * vy; aV1z += c2 * vz;
            q = qn;
        }
    }

    aS0  += __shfl_xor(aS0, 32);
    aS1  += __shfl_xor(aS1, 32);
    aV0x += __shfl_xor(aV0x, 32);
    aV0y += __shfl_xor(aV0y, 32);
    aV0z += __shfl_xor(aV0z, 32);
    aV1x += __shfl_xor(aV1x, 32);
    aV1y += __shfl_xor(aV1y, 32);
    aV1z += __shfl_xor(aV1z, 32);

    if (h == 0) {
        // SVb[n][u] packed: {S0,S1'} {V0x,V0y} {V0z,V1x} {V1y,V1z}
        uint4 o;
        o.x = pack_bf(aS0, aS1 * inv_sqrt3);
        o.y = pack_bf(aV0x, aV0y);
        o.z = pack_bf(aV0z, aV1x);
        o.w = pack_bf(aV1y, aV1z);
        *(uint4*)(SVb + (size_t)n * 256 + u * 8) = o;
    }
}

// ---------------- final linear only: out += (S@W2_s, V@W2_v) * l2 ---------
// 2 nodes share each weight unpack; 28 KB LDS -> 5 blk/CU.

__global__ __launch_bounds__(256) void node_final(
    const ushort* __restrict__ SVb, const float* __restrict__ W2_s,
    const float* __restrict__ W2_v, float* __restrict__ out, int N)
{
    __shared__ uint2 wqb[1024];          // 8 KB
    __shared__ v2f   svtp[8][2][32][5];  // 20 KB (pad 5: 2-way write alias)

    int g = threadIdx.x >> 5;
    int w = threadIdx.x & 31;

    for (int i = threadIdx.x; i < 1024; i += 256)  // i = u*32+w
        wqb[i] = (uint2){pack_bf(W2_s[i], W2_v[i]),
                         pack_bf(W2_s[i + 1024], W2_v[i + 1024])};
    __syncthreads();

    const float l2 = 0.125f;   // 1/sqrt(64)

    int n0 = blockIdx.x * 16 + g * 2;
    int n1 = n0 + 1;
    if (n0 < N) {
        uint4 p = *(const uint4*)(SVb + (size_t)n0 * 256 + w * 8);
        svtp[g][0][w][0] = (v2f){bf_lo(p.x), bf_lo(p.z)};   // {S0 , V0z}
        svtp[g][0][w][1] = (v2f){bf_hi(p.x), bf_hi(p.w)};   // {S1', V1z}
        svtp[g][0][w][2] = (v2f){bf_lo(p.y), bf_hi(p.y)};   // {V0x, V0y}
        svtp[g][0][w][3] = (v2f){bf_hi(p.z), bf_lo(p.w)};   // {V1x, V1y}
    }
    if (n1 < N) {
        uint4 p = *(const uint4*)(SVb + (size_t)n1 * 256 + w * 8);
        svtp[g][1][w][0] = (v2f){bf_lo(p.x), bf_lo(p.z)};
        svtp[g][1][w][1] = (v2f){bf_hi(p.x), bf_hi(p.w)};
        svtp[g][1][w][2] = (v2f){bf_lo(p.y), bf_hi(p.y)};
        svtp[g][1][w][3] = (v2f){bf_hi(p.z), bf_lo(p.w)};
    }
    // same-wave LDS visibility (32-lane group within one wave)

    v2f sa0 = (v2f){0.f, 0.f}, va0 = (v2f){0.f, 0.f};
    v2f sa1 = (v2f){0.f, 0.f}, va1 = (v2f){0.f, 0.f};
#pragma unroll
    for (int u = 0; u < 32; ++u) {
        uint2 qw = wqb[u * 32 + w];
        float w2s_a = bf_lo(qw.x), w2v_a = bf_hi(qw.x);
        float w2s_b = bf_lo(qw.y), w2v_b = bf_hi(qw.y);
        v2f wa  = (v2f){w2s_a, w2v_a};
        v2f wb  = (v2f){w2s_b, w2v_b};
        v2f wva = (v2f){w2v_a, w2v_a};
        v2f wvb = (v2f){w2v_b, w2v_b};
        sa0 += svtp[g][0][u][0] * wa;   // {sa += S0*W2s, va2 += V0z*W2v}
        sa0 += svtp[g][0][u][1] * wb;
        va0 += svtp[g][0][u][2] * wva;  // {va0 += V0x*W2v, va1 += V0y*W2v}
        va0 += svtp[g][0][u][3] * wvb;
        sa1 += svtp[g][1][u][0] * wa;
        sa1 += svtp[g][1][u][1] * wb;
        va1 += svtp[g][1][u][2] * wva;
        va1 += svtp[g][1][u][3] * wvb;
    }
    if (n0 < N) {
        float* orow = out + (size_t)n0 * 128;
        orow[w]              += sa0.x * l2;
        orow[32 + w * 3 + 0] += va0.x * l2;
        orow[32 + w * 3 + 1] += va0.y * l2;
        orow[32 + w * 3 + 2] += sa0.y * l2;
    }
    if (n1 < N) {
        float* orow = out + (size_t)n1 * 128;
        orow[w]              += sa1.x * l2;
        orow[32 + w * 3 + 0] += va1.x * l2;
        orow[32 + w * 3 + 1] += va1.y * l2;
        orow[32 + w * 3 + 2] += sa1.y * l2;
    }
}

// ---------------- fallback (atomic path, float SV) ----------------

__global__ __launch_bounds__(256) void edge_kernel(
    const float* __restrict__ ea, const float* __restrict__ ee,
    const float* __restrict__ fc1, const float* __restrict__ fc2,
    const ushort* __restrict__ sv1, const int* __restrict__ eidx,
    float* __restrict__ SV, int E)
{
    long long tid = (long long)blockIdx.x * 256 + threadIdx.x;
    int e = (int)(tid >> 5);
    int u = (int)(tid & 31);
    if (e >= E) return;
    const float rs8 = 0.35355339059327373f;
    const float inv_sqrt3 = 0.5773502691896258f;
    float ev[8];
#pragma unroll
    for (int i = 0; i < 8; ++i) ev[i] = ee[(size_t)e * 8 + i];
    float h[8];
#pragma unroll
    for (int k = 0; k < 8; ++k) {
        float t = 0.f;
#pragma unroll
        for (int i = 0; i < 8; ++i) t += ev[i] * fc1[i * 8 + k];
        t *= rs8;
        h[k] = t / (1.f + expf(-t));
    }
    float w0 = 0.f, w1 = 0.f, w2 = 0.f, w3 = 0.f;
#pragma unroll
    for (int k = 0; k < 8; ++k) {
        const float* f2 = fc2 + k * 128;
        float hk = h[k];
        w0 += hk * f2[u];
        w1 += hk * f2[32 + u];
        w2 += hk * f2[64 + u];
        w3 += hk * f2[96 + u];
    }
    w0 *= rs8; w1 *= rs8; w2 *= rs8; w3 *= rs8;
    int dst = eidx[e];
    int src = eidx[E + e];
    float a0 = ea[(size_t)e * 4 + 0];
    float ax = ea[(size_t)e * 4 + 1];
    float ay = ea[(size_t)e * 4 + 2];
    float az = ea[(size_t)e * 4 + 3];
    ushort4 q = *(const ushort4*)(sv1 + (size_t)src * 128 + u * 4);
    float ss = bf2f(q.x), vx = bf2f(q.y), vy = bf2f(q.z), vz = bf2f(q.w);
    float dv = vx * ax + vy * ay + vz * az;
    float* o = SV + (size_t)dst * 256 + u * 8;
    atomicAdd(o + 0, w0 * ss * a0);
    atomicAdd(o + 1, w3 * dv * inv_sqrt3);
    float c1 = w1 * ss;
    atomicAdd(o + 2, c1 * ax);
    atomicAdd(o + 3, c1 * ay);
    atomicAdd(o + 4, c1 * az);
    float c2 = w2 * a0;
    atomicAdd(o + 5, c2 * vx);
    atomicAdd(o + 6, c2 * vy);
    atomicAdd(o + 7, c2 * vz);
}

// fallback final: linear from f32 SV, += onto the skip node_prep wrote
__global__ __launch_bounds__(256) void node_final_f32(
    const float* __restrict__ SV, const float* __restrict__ W2_s,
    const float* __restrict__ W2_v, float* __restrict__ out, int N)
{
    __shared__ float wq[4096];
    __shared__ float svt[8][8][32];

    int g = threadIdx.x >> 5;
    int w = threadIdx.x & 31;

    for (int i = threadIdx.x; i < 1024; i += 256)
        *(float4*)&wq[i * 4] = make_float4(W2_s[i], W2_s[i + 1024],
                                           W2_v[i], W2_v[i + 1024]);
    __syncthreads();

    const float l2 = 0.125f;

    for (int t = 0; t < 4; ++t) {
        int n = blockIdx.x * 32 + g * 4 + t;
        if (n >= N) continue;
        const float* svp = SV + (size_t)n * 256 + w * 8;
        float4 p0 = *(const float4*)svp;
        float4 p1 = *(const float4*)(svp + 4);
        svt[g][0][w] = p0.x; svt[g][1][w] = p0.y;
        svt[g][2][w] = p0.z; svt[g][3][w] = p0.w;
        svt[g][4][w] = p1.x; svt[g][5][w] = p1.y;
        svt[g][6][w] = p1.z; svt[g][7][w] = p1.w;

        float sa = 0.f, va0 = 0.f, va1 = 0.f, va2 = 0.f;
#pragma unroll
        for (int u = 0; u < 32; ++u) {
            float4 qw = *(const float4*)&wq[(u * 32 + w) * 4];
            sa  += svt[g][0][u] * qw.x + svt[g][1][u] * qw.y;
            va0 += svt[g][2][u] * qw.z + svt[g][5][u] * qw.w;
            va1 += svt[g][3][u] * qw.z + svt[g][6][u] * qw.w;
            va2 += svt[g][4][u] * qw.z + svt[g][7][u] * qw.w;
        }
        float* orow = out + (size_t)n * 128;
        orow[w]              += sa  * l2;
        orow[32 + w * 3 + 0] += va0 * l2;
        orow[32 + w * 3 + 1] += va1 * l2;
        orow[32 + w * 3 + 2] += va2 * l2;
    }
}

extern "C" void kernel_launch(void* const* d_in, const int* in_sizes, int n_in,
                              void* d_out, int out_size, void* d_ws, size_t ws_size,
                              hipStream_t stream) {
    const float* nf    = (const float*)d_in[0];
    const float* nattr = (const float*)d_in[1];
    const float* ea    = (const float*)d_in[2];
    const float* ee    = (const float*)d_in[3];
    const float* W1_s  = (const float*)d_in[4];
    const float* W1_v  = (const float*)d_in[5];
    const float* fc1   = (const float*)d_in[6];
    const float* fc2   = (const float*)d_in[7];
    const float* W2_s  = (const float*)d_in[8];
    const float* W2_v  = (const float*)d_in[9];
    const float* Wsc_s = (const float*)d_in[10];
    const float* Wsc_v = (const float*)d_in[11];
    const int*   eidx  = (const int*)d_in[12];

    int N = in_sizes[0] / 128;
    int E = in_sizes[12] / 2;

    float* ws = (float*)d_ws;
    // main-path layout (float units)
    ushort* sv1 = (ushort*)ws;                         // N*128 ushorts (N*64 f)
    ushort* SVb = (ushort*)(ws + (size_t)N * 64);      // N*256 ushorts (N*128 f)
    unsigned* recb = (unsigned*)(ws + (size_t)N * 192); // E*8 uints
    int* cnt  = (int*)(ws + (size_t)N * 192 + (size_t)E * 8); // N
    int* rs   = cnt + N;                               // N
    int* bsum = rs + N;                                // 64
    int* boff = bsum + 64;                             // 64

    size_t needed = ((size_t)N * 194 + (size_t)E * 8 + 128) * 4;

    int nb_node = (N + 7) / 8;
    int nbE = (E + 255) / 256;

    if (ws_size >= needed) {
        hipMemsetAsync(cnt, 0, (size_t)N * sizeof(int), stream);
        node_prep<<<nb_node, 256, 0, stream>>>(nf, W1_s, W1_v, nattr, Wsc_s,
                                               Wsc_v, eidx, cnt, sv1,
                                               (float*)d_out, N, E);
        int nbS = (N + 1023) / 1024;
        scan_a<<<nbS, 1024, 0, stream>>>(cnt, rs, bsum, N);
        scan_b<<<1, 64, 0, stream>>>(bsum, boff, nbS);
        scatter_build<<<nbE, 256, 0, stream>>>(ea, ee, fc1, eidx, rs, boff,
                                               recb, E);
        reduce_kernel<<<N, 64, 0, stream>>>(fc2, sv1, recb, rs, boff, cnt,
                                            SVb, N);
        int nb_final = (N + 15) / 16;
        node_final<<<nb_final, 256, 0, stream>>>(SVb, W2_s, W2_v,
                                                 (float*)d_out, N);
    } else {
        // fallback: atomic path with float SV (node_prep still writes skip)
        float* SVf = ws + (size_t)N * 64;           // N*256 floats
        int* cnt_f = (int*)(SVf + (size_t)N * 256); // N
        hipMemsetAsync(SVf, 0, (size_t)N * 256 * sizeof(float), stream);
        hipMemsetAsync(cnt_f, 0, (size_t)N * sizeof(int), stream);
        node_prep<<<nb_node, 256, 0, stream>>>(nf, W1_s, W1_v, nattr, Wsc_s,
                                               Wsc_v, eidx, cnt_f, sv1,
                                               (float*)d_out, N, E);
        long long tot = (long long)E * 32;
        int nb_edge = (int)((tot + 255) / 256);
        edge_kernel<<<nb_edge, 256, 0, stream>>>(ea, ee, fc1, fc2, sv1, eidx, SVf, E);
        int nb_final_f = (N + 31) / 32;
        node_final_f32<<<nb_final_f, 256, 0, stream>>>(SVf, W2_s, W2_v,
                                                       (float*)d_out, N);
    }
}

// Round 18
// 232.627 us; speedup vs baseline: 1.2154x; 1.2154x over previous
//
#include <hip/hip_runtime.h>
#include <math.h>

// ---------------------------------------------------------------------------
// InteractionBlock: gather -> per-edge tensor-product -> scatter -> linear
// N=50000 nodes, E=800000 edges, MUL=32.
//
// Round-17 = R14 base + node_final split done right:
//  * node_prep: exact R14 (histogram + W1 linear -> bf16 sv1). No skip.
//  * NEW skip_kernel: out = skip, f32 Wsc v2f pairs in LDS (36KB, 4 blk/CU,
//    zero unpacks). Isolated so node_final & node_prep both stay lean.
//  * node_final: linear-only, 1 node/group (R14's proven 56-VGPR register
//    shape — R16's 2-node unroll hit 256 VGPR/10% occ), LDS 18KB
//    (wqb 8 + svtp 10) -> 8 blk/CU = 100% wave cap; out += linear.
//  * reduce (1 wave/node), scatter_build (32B records) unchanged from R14.
//
// ws layout (float units):
//   sv1[N*64] | SVb[N*128] | recb[E*8] | cnt[N] | rs[N] | bsum[64] | boff[64]
// ---------------------------------------------------------------------------

typedef float  v2f __attribute__((ext_vector_type(2)));
typedef float  v4f __attribute__((ext_vector_type(4)));

__device__ __forceinline__ unsigned short f2bf(float x) {
    unsigned u = __float_as_uint(x);
    u += 0x7FFFu + ((u >> 16) & 1u);   // RNE
    return (unsigned short)(u >> 16);
}
__device__ __forceinline__ float bf2f(unsigned short h) {
    return __uint_as_float(((unsigned)h) << 16);
}
__device__ __forceinline__ unsigned pack_bf(float lo, float hi) {
    unsigned ul = __float_as_uint(lo);
    ul = (ul + (0x7FFFu + ((ul >> 16) & 1u))) >> 16;
    unsigned uh = __float_as_uint(hi);
    uh = (uh + (0x7FFFu + ((uh >> 16) & 1u))) & 0xFFFF0000u;
    return ul | uh;
}
__device__ __forceinline__ float bf_lo(unsigned p) { return __uint_as_float(p << 16); }
__device__ __forceinline__ float bf_hi(unsigned p) { return __uint_as_float(p & 0xFFFF0000u); }

__global__ __launch_bounds__(256) void node_prep(
    const float* __restrict__ nf, const float* __restrict__ W1_s,
    const float* __restrict__ W1_v, const int* __restrict__ eidx,
    int* __restrict__ cnt, ushort* __restrict__ sv1, int N, int E)
{
    __shared__ float w1s[1024];
    __shared__ float w1v[1024];
    __shared__ float nrow[8][128];

    // folded histogram of dst
    for (long long e = (long long)blockIdx.x * 256 + threadIdx.x; e < E;
         e += (long long)gridDim.x * 256)
        atomicAdd(cnt + eidx[(int)e], 1);

    int g = threadIdx.x >> 5;
    int w = threadIdx.x & 31;
    int n = blockIdx.x * 8 + g;

    for (int i = threadIdx.x; i < 1024; i += 256) {
        w1s[i] = W1_s[i];
        w1v[i] = W1_v[i];
    }
    if (n < N) {
        float4 q = *(const float4*)(nf + (size_t)n * 128 + w * 4);
        *(float4*)&nrow[g][w * 4] = q;
    }
    __syncthreads();
    if (n >= N) return;

    const float l1 = 0.17677669529663687f; // 1/sqrt(32)
    const float* r = nrow[g];
    float ss = 0.f, vx = 0.f, vy = 0.f, vz = 0.f;
#pragma unroll 8
    for (int u = 0; u < 32; ++u) {
        float ws = w1s[u * 32 + w];
        float wv = w1v[u * 32 + w];
        ss += r[u] * ws;
        vx += r[32 + u * 3 + 0] * wv;
        vy += r[32 + u * 3 + 1] * wv;
        vz += r[32 + u * 3 + 2] * wv;
    }
    ushort4 o;
    o.x = f2bf(ss * l1); o.y = f2bf(vx * l1);
    o.z = f2bf(vy * l1); o.w = f2bf(vz * l1);
    *(ushort4*)(sv1 + (size_t)n * 128 + w * 4) = o;
}

// ---------------- skip connection: out = einsum(nf, nattr, Wsc) -----------

__global__ __launch_bounds__(256) void skip_kernel(
    const float* __restrict__ nf, const float* __restrict__ nattr,
    const float* __restrict__ Wsc_s, const float* __restrict__ Wsc_v,
    float* __restrict__ out, int N)
{
    __shared__ v2f ws_s01[1024];     // 8 KB {Wsc_s[u][0][w], Wsc_s[u][1][w]}
    __shared__ v2f ws_s23[1024];     // 8 KB
    __shared__ v2f ws_v01[1024];     // 8 KB
    __shared__ v2f ws_v23[1024];     // 8 KB
    __shared__ float nrow[8][128];   // 4 KB -> 36 KB total, 4 blk/CU

    int g = threadIdx.x >> 5;
    int w = threadIdx.x & 31;

    for (int i = threadIdx.x; i < 1024; i += 256) {
        int uu = i >> 5, ww = i & 31;
        const float* ps = Wsc_s + (size_t)uu * 128 + ww;
        const float* pv = Wsc_v + (size_t)uu * 128 + ww;
        ws_s01[i] = (v2f){ps[0],  ps[32]};
        ws_s23[i] = (v2f){ps[64], ps[96]};
        ws_v01[i] = (v2f){pv[0],  pv[32]};
        ws_v23[i] = (v2f){pv[64], pv[96]};
    }
    int n = blockIdx.x * 8 + g;
    if (n < N) {
        float4 q = *(const float4*)(nf + (size_t)n * 128 + w * 4);
        *(float4*)&nrow[g][w * 4] = q;
    }
    __syncthreads();
    if (n >= N) return;

    const float sc_norm = 0.08838834764831843f; // 1/sqrt(128)
    v2f at01 = (v2f){nattr[(size_t)n * 4 + 0], nattr[(size_t)n * 4 + 1]};
    v2f at23 = (v2f){nattr[(size_t)n * 4 + 2], nattr[(size_t)n * 4 + 3]};

    const float* r = nrow[g];
    float scs = 0.f, scv0 = 0.f, scv1 = 0.f, scv2 = 0.f;
#pragma unroll 8
    for (int u = 0; u < 32; ++u) {
        int idx = u * 32 + w;
        v2f ts = at01 * ws_s01[idx] + at23 * ws_s23[idx];
        v2f tv = at01 * ws_v01[idx] + at23 * ws_v23[idx];
        float cs = ts.x + ts.y;
        float cv = tv.x + tv.y;
        scs  += r[u] * cs;
        scv0 += r[32 + u * 3 + 0] * cv;
        scv1 += r[32 + u * 3 + 1] * cv;
        scv2 += r[32 + u * 3 + 2] * cv;
    }
    float* orow = out + (size_t)n * 128;
    orow[w]              = scs  * sc_norm;
    orow[32 + w * 3 + 0] = scv0 * sc_norm;
    orow[32 + w * 3 + 1] = scv1 * sc_norm;
    orow[32 + w * 3 + 2] = scv2 * sc_norm;
}

// ---------------- CSR build ----------------

__global__ __launch_bounds__(1024) void scan_a(
    const int* __restrict__ cnt, int* __restrict__ rs,
    int* __restrict__ bsum, int N)
{
    int i = blockIdx.x * 1024 + threadIdx.x;
    int lane = threadIdx.x & 63;
    int wid = threadIdx.x >> 6;
    int v = (i < N) ? cnt[i] : 0;
    int incl = v;
#pragma unroll
    for (int d = 1; d < 64; d <<= 1) {
        int t = __shfl_up(incl, d);
        if (lane >= d) incl += t;
    }
    __shared__ int wtot[16];
    __shared__ int woff[16];
    if (lane == 63) wtot[wid] = incl;
    __syncthreads();
    if (wid == 0) {
        int t = (lane < 16) ? wtot[lane] : 0;
        int s = t;
#pragma unroll
        for (int d = 1; d < 16; d <<= 1) {
            int q = __shfl_up(s, d);
            if (lane >= d) s += q;
        }
        if (lane < 16) woff[lane] = s - t;
        if (lane == 15) bsum[blockIdx.x] = s;
    }
    __syncthreads();
    if (i < N) rs[i] = woff[wid] + incl - v;   // block-local exclusive prefix
}

__global__ __launch_bounds__(64) void scan_b(
    const int* __restrict__ bsum, int* __restrict__ boff, int nb)
{
    int lane = threadIdx.x;
    int carry = 0;
    for (int base = 0; base < nb; base += 64) {
        int i = base + lane;
        int v = (i < nb) ? bsum[i] : 0;
        int s = v;
#pragma unroll
        for (int d = 1; d < 64; d <<= 1) {
            int t = __shfl_up(s, d);
            if (lane >= d) s += t;
        }
        if (i < nb) boff[i] = carry + s - v;
        carry += __shfl(s, 63);
    }
}

// fused scatter + edge-MLP: sequential reads; ONE 32B record per edge at the
// dst-sorted position (2 adjacent b128 stores -> 1 cache line touched).
__global__ __launch_bounds__(256) void scatter_build(
    const float* __restrict__ ea, const float* __restrict__ ee,
    const float* __restrict__ fc1, const int* __restrict__ eidx,
    int* __restrict__ rs, const int* __restrict__ boff,
    unsigned* __restrict__ recb, int E)
{
    int e = blockIdx.x * 256 + threadIdx.x;
    if (e >= E) return;
    const float rs8 = 0.35355339059327373f;   // 1/sqrt(8)

    int d = eidx[e];
    int src = eidx[E + e];
    int p = atomicAdd(rs + d, 1) + boff[d >> 10];

    const float* eep = ee + (size_t)e * 8;
    v4f e0 = *(const v4f*)eep;
    v4f e1 = *(const v4f*)(eep + 4);
    float ev[8] = {e0.x, e0.y, e0.z, e0.w, e1.x, e1.y, e1.z, e1.w};
    float hh[8];
#pragma unroll
    for (int k = 0; k < 8; ++k) {
        float t = 0.f;
#pragma unroll
        for (int i = 0; i < 8; ++i) t += ev[i] * fc1[i * 8 + k];
        t *= rs8;
        hh[k] = t * __builtin_amdgcn_rcpf(1.f + __expf(-t)) * rs8; // silu, rs8 folded
    }
    uint4 hp;
    hp.x = pack_bf(hh[0], hh[1]);
    hp.y = pack_bf(hh[2], hh[3]);
    hp.z = pack_bf(hh[4], hh[5]);
    hp.w = pack_bf(hh[6], hh[7]);
    v4f a = *(const v4f*)(ea + (size_t)e * 4);
    uint4 t2;
    t2.x = pack_bf(a.x, a.y);
    t2.y = pack_bf(a.z, a.w);
    t2.z = (unsigned)src;
    t2.w = 0u;
    unsigned* rp = recb + (size_t)p * 8;
    *(uint4*)rp       = hp;
    *(uint4*)(rp + 4) = t2;
}

// ---------------- per-node reduction (no atomics, 1 wave = 1 node) --------

__global__ __launch_bounds__(64) void reduce_kernel(
    const float* __restrict__ fc2, const ushort* __restrict__ sv1,
    const unsigned* __restrict__ recb, const int* __restrict__ rs_end,
    const int* __restrict__ boff, const int* __restrict__ cnt,
    ushort* __restrict__ SVb, int N)
{
    __shared__ float rec[64][20];   // 5.1 KB -> wave-granular scheduling

    int l = threadIdx.x;
    int h = l >> 5;
    int u = l & 31;
    int n = blockIdx.x;

    const float inv_sqrt3 = 0.5773502691896258f;

    v2f f01[8], f23[8];
#pragma unroll
    for (int k = 0; k < 8; ++k) {
        f01[k].x = fc2[k * 128 + u];
        f01[k].y = fc2[k * 128 + 32 + u];
        f23[k].x = fc2[k * 128 + 64 + u];
        f23[k].y = fc2[k * 128 + 96 + u];
    }

    int count = cnt[n];
    int start = rs_end[n] + boff[n >> 10] - count;

    float aS0 = 0.f, aS1 = 0.f;
    float aV0x = 0.f, aV0y = 0.f, aV0z = 0.f;
    float aV1x = 0.f, aV1y = 0.f, aV1z = 0.f;

    for (int j0 = 0; j0 < count; j0 += 64) {
        int nk = count - j0; if (nk > 64) nk = 64;
        // phase 1: coalesced 32B record load + unpack (MLP precomputed)
        if (l < nk) {
            const unsigned* rp = recb + (size_t)(start + j0 + l) * 8;
            uint4 hq = *(const uint4*)rp;
            uint4 aq = *(const uint4*)(rp + 4);
            float* rr = &rec[l][0];
            *(v4f*)rr       = (v4f){bf_lo(hq.x), bf_hi(hq.x), bf_lo(hq.y), bf_hi(hq.y)};
            *(v4f*)(rr + 4) = (v4f){bf_lo(hq.z), bf_hi(hq.z), bf_lo(hq.w), bf_hi(hq.w)};
            *(v4f*)(rr + 8) = (v4f){bf_lo(aq.x), bf_hi(aq.x), bf_lo(aq.y), bf_hi(aq.y)};
            rr[12] = __uint_as_float(aq.z);
        }
        // phase 2: 2 edges/iteration (h picks the edge), branchless 1-deep
        // sv1-row prefetch.
        int pairs = (nk + 1) >> 1;
        int last = nk - 1;
        int s0 = __float_as_int(rec[h <= last ? h : last][12]);
        ushort4 q = *(const ushort4*)(sv1 + (size_t)s0 * 128 + u * 4);
        for (int jj = 0; jj < pairs; ++jj) {
            int slot = jj * 2 + h;
            int nslot = slot + 2 <= last ? slot + 2 : last;
            int sN = __float_as_int(rec[nslot][12]);
            ushort4 qn = *(const ushort4*)(sv1 + (size_t)sN * 128 + u * 4);

            float msk = (slot <= last) ? 1.f : 0.f;
            int slotc = slot <= last ? slot : last;
            const float* rr = &rec[slotc][0];
            v4f H0 = *(const v4f*)rr;
            v4f H1 = *(const v4f*)(rr + 4);
            v4f A  = *(const v4f*)(rr + 8);
            float ss = bf2f(q.x) * msk;
            float vx = bf2f(q.y), vy = bf2f(q.z), vz = bf2f(q.w);

            v2f w01 = H0.x * f01[0] + H0.y * f01[1] + H0.z * f01[2] + H0.w * f01[3]
                    + H1.x * f01[4] + H1.y * f01[5] + H1.z * f01[6] + H1.w * f01[7];
            v2f w23 = H0.x * f23[0] + H0.y * f23[1] + H0.z * f23[2] + H0.w * f23[3]
                    + H1.x * f23[4] + H1.y * f23[5] + H1.z * f23[6] + H1.w * f23[7];

            float dv = (vx * A.y + vy * A.z + vz * A.w) * msk;
            aS0 += w01.x * (ss * A.x);
            aS1 += w23.y * dv;
            float c1 = w01.y * ss;
            aV0x += c1 * A.y; aV0y += c1 * A.z; aV0z += c1 * A.w;
            float c2 = w23.x * A.x * msk;
            aV1x += c2 * vx; aV1y += c2 * vy; aV1z += c2 * vz;
            q = qn;
        }
    }

    aS0  += __shfl_xor(aS0, 32);
    aS1  += __shfl_xor(aS1, 32);
    aV0x += __shfl_xor(aV0x, 32);
    aV0y += __shfl_xor(aV0y, 32);
    aV0z += __shfl_xor(aV0z, 32);
    aV1x += __shfl_xor(aV1x, 32);
    aV1y += __shfl_xor(aV1y, 32);
    aV1z += __shfl_xor(aV1z, 32);

    if (h == 0) {
        // SVb[n][u] packed: {S0,S1'} {V0x,V0y} {V0z,V1x} {V1y,V1z}
        uint4 o;
        o.x = pack_bf(aS0, aS1 * inv_sqrt3);
        o.y = pack_bf(aV0x, aV0y);
        o.z = pack_bf(aV0z, aV1x);
        o.w = pack_bf(aV1y, aV1z);
        *(uint4*)(SVb + (size_t)n * 256 + u * 8) = o;
    }
}

// ---------------- final linear only: out += (S@W2_s, V@W2_v) * l2 ---------
// 1 node per 32-lane group (R14-proven register shape), 18 KB -> 8 blk/CU.

__global__ __launch_bounds__(256) void node_final(
    const ushort* __restrict__ SVb, const float* __restrict__ W2_s,
    const float* __restrict__ W2_v, float* __restrict__ out, int N)
{
    __shared__ uint2 wqb[1024];       // 8 KB
    __shared__ v2f   svtp[8][32][5];  // 10 KB (pad 5: 2-way write alias)

    int g = threadIdx.x >> 5;
    int w = threadIdx.x & 31;

    for (int i = threadIdx.x; i < 1024; i += 256)  // i = u*32+w
        wqb[i] = (uint2){pack_bf(W2_s[i], W2_v[i]),
                         pack_bf(W2_s[i + 1024], W2_v[i + 1024])};
    __syncthreads();

    const float l2 = 0.125f;   // 1/sqrt(64)
    int n = blockIdx.x * 8 + g;
    if (n >= N) return;

    // stage SV row as the 4 pairs the pk_fma loop needs:
    uint4 p = *(const uint4*)(SVb + (size_t)n * 256 + w * 8);
    svtp[g][w][0] = (v2f){bf_lo(p.x), bf_lo(p.z)};   // {S0 , V0z}
    svtp[g][w][1] = (v2f){bf_hi(p.x), bf_hi(p.w)};   // {S1', V1z}
    svtp[g][w][2] = (v2f){bf_lo(p.y), bf_hi(p.y)};   // {V0x, V0y}
    svtp[g][w][3] = (v2f){bf_hi(p.z), bf_lo(p.w)};   // {V1x, V1y}
    // same-wave LDS visibility (32-lane group within one wave)

    v2f sa_va2 = (v2f){0.f, 0.f};
    v2f va01   = (v2f){0.f, 0.f};
#pragma unroll
    for (int u = 0; u < 32; ++u) {
        uint2 qw = wqb[u * 32 + w];
        float w2s_a = bf_lo(qw.x), w2v_a = bf_hi(qw.x);
        float w2s_b = bf_lo(qw.y), w2v_b = bf_hi(qw.y);
        sa_va2 += svtp[g][u][0] * (v2f){w2s_a, w2v_a};  // {sa+=S0*W2s, va2+=V0z*W2v}
        sa_va2 += svtp[g][u][1] * (v2f){w2s_b, w2v_b};
        va01   += svtp[g][u][2] * (v2f){w2v_a, w2v_a};  // {va0+=V0x*W2v, va1+=V0y*W2v}
        va01   += svtp[g][u][3] * (v2f){w2v_b, w2v_b};
    }
    float* orow = out + (size_t)n * 128;
    orow[w]              += sa_va2.x * l2;
    orow[32 + w * 3 + 0] += va01.x   * l2;
    orow[32 + w * 3 + 1] += va01.y   * l2;
    orow[32 + w * 3 + 2] += sa_va2.y * l2;
}

// ---------------- fallback (atomic path, float SV) ----------------

__global__ __launch_bounds__(256) void edge_kernel(
    const float* __restrict__ ea, const float* __restrict__ ee,
    const float* __restrict__ fc1, const float* __restrict__ fc2,
    const ushort* __restrict__ sv1, const int* __restrict__ eidx,
    float* __restrict__ SV, int E)
{
    long long tid = (long long)blockIdx.x * 256 + threadIdx.x;
    int e = (int)(tid >> 5);
    int u = (int)(tid & 31);
    if (e >= E) return;
    const float rs8 = 0.35355339059327373f;
    const float inv_sqrt3 = 0.5773502691896258f;
    float ev[8];
#pragma unroll
    for (int i = 0; i < 8; ++i) ev[i] = ee[(size_t)e * 8 + i];
    float h[8];
#pragma unroll
    for (int k = 0; k < 8; ++k) {
        float t = 0.f;
#pragma unroll
        for (int i = 0; i < 8; ++i) t += ev[i] * fc1[i * 8 + k];
        t *= rs8;
        h[k] = t / (1.f + expf(-t));
    }
    float w0 = 0.f, w1 = 0.f, w2 = 0.f, w3 = 0.f;
#pragma unroll
    for (int k = 0; k < 8; ++k) {
        const float* f2 = fc2 + k * 128;
        float hk = h[k];
        w0 += hk * f2[u];
        w1 += hk * f2[32 + u];
        w2 += hk * f2[64 + u];
        w3 += hk * f2[96 + u];
    }
    w0 *= rs8; w1 *= rs8; w2 *= rs8; w3 *= rs8;
    int dst = eidx[e];
    int src = eidx[E + e];
    float a0 = ea[(size_t)e * 4 + 0];
    float ax = ea[(size_t)e * 4 + 1];
    float ay = ea[(size_t)e * 4 + 2];
    float az = ea[(size_t)e * 4 + 3];
    ushort4 q = *(const ushort4*)(sv1 + (size_t)src * 128 + u * 4);
    float ss = bf2f(q.x), vx = bf2f(q.y), vy = bf2f(q.z), vz = bf2f(q.w);
    float dv = vx * ax + vy * ay + vz * az;
    float* o = SV + (size_t)dst * 256 + u * 8;
    atomicAdd(o + 0, w0 * ss * a0);
    atomicAdd(o + 1, w3 * dv * inv_sqrt3);
    float c1 = w1 * ss;
    atomicAdd(o + 2, c1 * ax);
    atomicAdd(o + 3, c1 * ay);
    atomicAdd(o + 4, c1 * az);
    float c2 = w2 * a0;
    atomicAdd(o + 5, c2 * vx);
    atomicAdd(o + 6, c2 * vy);
    atomicAdd(o + 7, c2 * vz);
}

// fallback final: linear from f32 SV, += onto the skip skip_kernel wrote
__global__ __launch_bounds__(256) void node_final_f32(
    const float* __restrict__ SV, const float* __restrict__ W2_s,
    const float* __restrict__ W2_v, float* __restrict__ out, int N)
{
    __shared__ float wq[4096];
    __shared__ float svt[8][8][32];

    int g = threadIdx.x >> 5;
    int w = threadIdx.x & 31;

    for (int i = threadIdx.x; i < 1024; i += 256)
        *(float4*)&wq[i * 4] = make_float4(W2_s[i], W2_s[i + 1024],
                                           W2_v[i], W2_v[i + 1024]);
    __syncthreads();

    const float l2 = 0.125f;

    for (int t = 0; t < 4; ++t) {
        int n = blockIdx.x * 32 + g * 4 + t;
        if (n >= N) continue;
        const float* svp = SV + (size_t)n * 256 + w * 8;
        float4 p0 = *(const float4*)svp;
        float4 p1 = *(const float4*)(svp + 4);
        svt[g][0][w] = p0.x; svt[g][1][w] = p0.y;
        svt[g][2][w] = p0.z; svt[g][3][w] = p0.w;
        svt[g][4][w] = p1.x; svt[g][5][w] = p1.y;
        svt[g][6][w] = p1.z; svt[g][7][w] = p1.w;

        float sa = 0.f, va0 = 0.f, va1 = 0.f, va2 = 0.f;
#pragma unroll
        for (int u = 0; u < 32; ++u) {
            float4 qw = *(const float4*)&wq[(u * 32 + w) * 4];
            sa  += svt[g][0][u] * qw.x + svt[g][1][u] * qw.y;
            va0 += svt[g][2][u] * qw.z + svt[g][5][u] * qw.w;
            va1 += svt[g][3][u] * qw.z + svt[g][6][u] * qw.w;
            va2 += svt[g][4][u] * qw.z + svt[g][7][u] * qw.w;
        }
        float* orow = out + (size_t)n * 128;
        orow[w]              += sa  * l2;
        orow[32 + w * 3 + 0] += va0 * l2;
        orow[32 + w * 3 + 1] += va1 * l2;
        orow[32 + w * 3 + 2] += va2 * l2;
    }
}

extern "C" void kernel_launch(void* const* d_in, const int* in_sizes, int n_in,
                              void* d_out, int out_size, void* d_ws, size_t ws_size,
                              hipStream_t stream) {
    const float* nf    = (const float*)d_in[0];
    const float* nattr = (const float*)d_in[1];
    const float* ea    = (const float*)d_in[2];
    const float* ee    = (const float*)d_in[3];
    const float* W1_s  = (const float*)d_in[4];
    const float* W1_v  = (const float*)d_in[5];
    const float* fc1   = (const float*)d_in[6];
    const float* fc2   = (const float*)d_in[7];
    const float* W2_s  = (const float*)d_in[8];
    const float* W2_v  = (const float*)d_in[9];
    const float* Wsc_s = (const float*)d_in[10];
    const float* Wsc_v = (const float*)d_in[11];
    const int*   eidx  = (const int*)d_in[12];

    int N = in_sizes[0] / 128;
    int E = in_sizes[12] / 2;

    float* ws = (float*)d_ws;
    // main-path layout (float units)
    ushort* sv1 = (ushort*)ws;                         // N*128 ushorts (N*64 f)
    ushort* SVb = (ushort*)(ws + (size_t)N * 64);      // N*256 ushorts (N*128 f)
    unsigned* recb = (unsigned*)(ws + (size_t)N * 192); // E*8 uints
    int* cnt  = (int*)(ws + (size_t)N * 192 + (size_t)E * 8); // N
    int* rs   = cnt + N;                               // N
    int* bsum = rs + N;                                // 64
    int* boff = bsum + 64;                             // 64

    size_t needed = ((size_t)N * 194 + (size_t)E * 8 + 128) * 4;

    int nb_node = (N + 7) / 8;
    int nbE = (E + 255) / 256;

    if (ws_size >= needed) {
        hipMemsetAsync(cnt, 0, (size_t)N * sizeof(int), stream);
        node_prep<<<nb_node, 256, 0, stream>>>(nf, W1_s, W1_v, eidx, cnt, sv1, N, E);
        int nbS = (N + 1023) / 1024;
        scan_a<<<nbS, 1024, 0, stream>>>(cnt, rs, bsum, N);
        scan_b<<<1, 64, 0, stream>>>(bsum, boff, nbS);
        scatter_build<<<nbE, 256, 0, stream>>>(ea, ee, fc1, eidx, rs, boff,
                                               recb, E);
        reduce_kernel<<<N, 64, 0, stream>>>(fc2, sv1, recb, rs, boff, cnt,
                                            SVb, N);
        skip_kernel<<<nb_node, 256, 0, stream>>>(nf, nattr, Wsc_s, Wsc_v,
                                                 (float*)d_out, N);
        node_final<<<nb_node, 256, 0, stream>>>(SVb, W2_s, W2_v,
                                                (float*)d_out, N);
    } else {
        // fallback: atomic path with float SV
        float* SVf = ws + (size_t)N * 64;           // N*256 floats
        int* cnt_f = (int*)(SVf + (size_t)N * 256); // N
        hipMemsetAsync(SVf, 0, (size_t)N * 256 * sizeof(float), stream);
        hipMemsetAsync(cnt_f, 0, (size_t)N * sizeof(int), stream);
        node_prep<<<nb_node, 256, 0, stream>>>(nf, W1_s, W1_v, eidx, cnt_f, sv1, N, E);
        long long tot = (long long)E * 32;
        int nb_edge = (int)((tot + 255) / 256);
        edge_kernel<<<nb_edge, 256, 0, stream>>>(ea, ee, fc1, fc2, sv1, eidx, SVf, E);
        skip_kernel<<<nb_node, 256, 0, stream>>>(nf, nattr, Wsc_s, Wsc_v,
                                                 (float*)d_out, N);
        int nb_final_f = (N + 31) / 32;
        node_final_f32<<<nb_final_f, 256, 0, stream>>>(SVf, W2_s, W2_v,
                                                       (float*)d_out, N);
    }
}

// Round 19
// 225.638 us; speedup vs baseline: 1.2530x; 1.0310x over previous
//
#include <hip/hip_runtime.h>
#include <math.h>

// ---------------------------------------------------------------------------
// InteractionBlock: gather -> per-edge tensor-product -> scatter -> linear
// N=50000 nodes, E=800000 edges, MUL=32.
//
// Round-18 = R17 kernels, serialization removed:
//  * scatter_build + skip fused into ONE heterogeneous launch: blocks < nbE
//    run scatter_build (latency/atomic-bound, ~4-17% VALU), blocks >= nbE run
//    the skip einsum (VALU-bound, f32 Wsc in LDS). Skip waves fill scatter's
//    latency bubbles instead of a serial 25us dispatch (R17's regression).
//  * node_prep (hist + W1 -> bf16 sv1), scans, reduce (1 wave/node, 32B
//    records), lean linear-only node_final (+=) all unchanged from R14/R17.
//
// ws layout (float units):
//   sv1[N*64] | SVb[N*128] | recb[E*8] | cnt[N] | rs[N] | bsum[64] | boff[64]
// ---------------------------------------------------------------------------

typedef float  v2f __attribute__((ext_vector_type(2)));
typedef float  v4f __attribute__((ext_vector_type(4)));

__device__ __forceinline__ unsigned short f2bf(float x) {
    unsigned u = __float_as_uint(x);
    u += 0x7FFFu + ((u >> 16) & 1u);   // RNE
    return (unsigned short)(u >> 16);
}
__device__ __forceinline__ float bf2f(unsigned short h) {
    return __uint_as_float(((unsigned)h) << 16);
}
__device__ __forceinline__ unsigned pack_bf(float lo, float hi) {
    unsigned ul = __float_as_uint(lo);
    ul = (ul + (0x7FFFu + ((ul >> 16) & 1u))) >> 16;
    unsigned uh = __float_as_uint(hi);
    uh = (uh + (0x7FFFu + ((uh >> 16) & 1u))) & 0xFFFF0000u;
    return ul | uh;
}
__device__ __forceinline__ float bf_lo(unsigned p) { return __uint_as_float(p << 16); }
__device__ __forceinline__ float bf_hi(unsigned p) { return __uint_as_float(p & 0xFFFF0000u); }

__global__ __launch_bounds__(256) void node_prep(
    const float* __restrict__ nf, const float* __restrict__ W1_s,
    const float* __restrict__ W1_v, const int* __restrict__ eidx,
    int* __restrict__ cnt, ushort* __restrict__ sv1, int N, int E)
{
    __shared__ float w1s[1024];
    __shared__ float w1v[1024];
    __shared__ float nrow[8][128];

    // folded histogram of dst
    for (long long e = (long long)blockIdx.x * 256 + threadIdx.x; e < E;
         e += (long long)gridDim.x * 256)
        atomicAdd(cnt + eidx[(int)e], 1);

    int g = threadIdx.x >> 5;
    int w = threadIdx.x & 31;
    int n = blockIdx.x * 8 + g;

    for (int i = threadIdx.x; i < 1024; i += 256) {
        w1s[i] = W1_s[i];
        w1v[i] = W1_v[i];
    }
    if (n < N) {
        float4 q = *(const float4*)(nf + (size_t)n * 128 + w * 4);
        *(float4*)&nrow[g][w * 4] = q;
    }
    __syncthreads();
    if (n >= N) return;

    const float l1 = 0.17677669529663687f; // 1/sqrt(32)
    const float* r = nrow[g];
    float ss = 0.f, vx = 0.f, vy = 0.f, vz = 0.f;
#pragma unroll 8
    for (int u = 0; u < 32; ++u) {
        float ws = w1s[u * 32 + w];
        float wv = w1v[u * 32 + w];
        ss += r[u] * ws;
        vx += r[32 + u * 3 + 0] * wv;
        vy += r[32 + u * 3 + 1] * wv;
        vz += r[32 + u * 3 + 2] * wv;
    }
    ushort4 o;
    o.x = f2bf(ss * l1); o.y = f2bf(vx * l1);
    o.z = f2bf(vy * l1); o.w = f2bf(vz * l1);
    *(ushort4*)(sv1 + (size_t)n * 128 + w * 4) = o;
}

// ---------------- CSR build ----------------

__global__ __launch_bounds__(1024) void scan_a(
    const int* __restrict__ cnt, int* __restrict__ rs,
    int* __restrict__ bsum, int N)
{
    int i = blockIdx.x * 1024 + threadIdx.x;
    int lane = threadIdx.x & 63;
    int wid = threadIdx.x >> 6;
    int v = (i < N) ? cnt[i] : 0;
    int incl = v;
#pragma unroll
    for (int d = 1; d < 64; d <<= 1) {
        int t = __shfl_up(incl, d);
        if (lane >= d) incl += t;
    }
    __shared__ int wtot[16];
    __shared__ int woff[16];
    if (lane == 63) wtot[wid] = incl;
    __syncthreads();
    if (wid == 0) {
        int t = (lane < 16) ? wtot[lane] : 0;
        int s = t;
#pragma unroll
        for (int d = 1; d < 16; d <<= 1) {
            int q = __shfl_up(s, d);
            if (lane >= d) s += q;
        }
        if (lane < 16) woff[lane] = s - t;
        if (lane == 15) bsum[blockIdx.x] = s;
    }
    __syncthreads();
    if (i < N) rs[i] = woff[wid] + incl - v;   // block-local exclusive prefix
}

__global__ __launch_bounds__(64) void scan_b(
    const int* __restrict__ bsum, int* __restrict__ boff, int nb)
{
    int lane = threadIdx.x;
    int carry = 0;
    for (int base = 0; base < nb; base += 64) {
        int i = base + lane;
        int v = (i < nb) ? bsum[i] : 0;
        int s = v;
#pragma unroll
        for (int d = 1; d < 64; d <<= 1) {
            int t = __shfl_up(s, d);
            if (lane >= d) s += t;
        }
        if (i < nb) boff[i] = carry + s - v;
        carry += __shfl(s, 63);
    }
}

// ---------------- fused scatter_build + skip (heterogeneous blocks) -------
// blocks < nbE: scatter+MLP -> 32B record at dst-sorted position (no LDS).
// blocks >= nbE: skip einsum (f32 Wsc v2f pairs in LDS) -> out = skip.
// Independent outputs (recb vs out); skip's VALU fills scatter's latency.

__global__ __launch_bounds__(256) void scatter_build_skip(
    const float* __restrict__ ea, const float* __restrict__ ee,
    const float* __restrict__ fc1, const int* __restrict__ eidx,
    int* __restrict__ rs, const int* __restrict__ boff,
    unsigned* __restrict__ recb, int E, int nbE,
    const float* __restrict__ nf, const float* __restrict__ nattr,
    const float* __restrict__ Wsc_s, const float* __restrict__ Wsc_v,
    float* __restrict__ out, int N)
{
    __shared__ v2f ws_s01[1024];     // 8 KB (skip blocks only)
    __shared__ v2f ws_s23[1024];     // 8 KB
    __shared__ v2f ws_v01[1024];     // 8 KB
    __shared__ v2f ws_v23[1024];     // 8 KB
    __shared__ float nrow[8][128];   // 4 KB -> 36 KB

    if ((int)blockIdx.x < nbE) {
        // ---- scatter_build ----
        int e = blockIdx.x * 256 + threadIdx.x;
        if (e >= E) return;
        const float rs8 = 0.35355339059327373f;   // 1/sqrt(8)

        int d = eidx[e];
        int src = eidx[E + e];
        int p = atomicAdd(rs + d, 1) + boff[d >> 10];

        const float* eep = ee + (size_t)e * 8;
        v4f e0 = *(const v4f*)eep;
        v4f e1 = *(const v4f*)(eep + 4);
        float ev[8] = {e0.x, e0.y, e0.z, e0.w, e1.x, e1.y, e1.z, e1.w};
        float hh[8];
#pragma unroll
        for (int k = 0; k < 8; ++k) {
            float t = 0.f;
#pragma unroll
            for (int i = 0; i < 8; ++i) t += ev[i] * fc1[i * 8 + k];
            t *= rs8;
            hh[k] = t * __builtin_amdgcn_rcpf(1.f + __expf(-t)) * rs8;
        }
        uint4 hp;
        hp.x = pack_bf(hh[0], hh[1]);
        hp.y = pack_bf(hh[2], hh[3]);
        hp.z = pack_bf(hh[4], hh[5]);
        hp.w = pack_bf(hh[6], hh[7]);
        v4f a = *(const v4f*)(ea + (size_t)e * 4);
        uint4 t2;
        t2.x = pack_bf(a.x, a.y);
        t2.y = pack_bf(a.z, a.w);
        t2.z = (unsigned)src;
        t2.w = 0u;
        unsigned* rp = recb + (size_t)p * 8;
        *(uint4*)rp       = hp;
        *(uint4*)(rp + 4) = t2;
    } else {
        // ---- skip connection: out = einsum(nf, nattr, Wsc) * sc_norm ----
        int b = blockIdx.x - nbE;
        int g = threadIdx.x >> 5;
        int w = threadIdx.x & 31;

        for (int i = threadIdx.x; i < 1024; i += 256) {
            int uu = i >> 5, ww = i & 31;
            const float* ps = Wsc_s + (size_t)uu * 128 + ww;
            const float* pv = Wsc_v + (size_t)uu * 128 + ww;
            ws_s01[i] = (v2f){ps[0],  ps[32]};
            ws_s23[i] = (v2f){ps[64], ps[96]};
            ws_v01[i] = (v2f){pv[0],  pv[32]};
            ws_v23[i] = (v2f){pv[64], pv[96]};
        }
        int n = b * 8 + g;
        if (n < N) {
            float4 q = *(const float4*)(nf + (size_t)n * 128 + w * 4);
            *(float4*)&nrow[g][w * 4] = q;
        }
        __syncthreads();
        if (n >= N) return;

        const float sc_norm = 0.08838834764831843f; // 1/sqrt(128)
        v2f at01 = (v2f){nattr[(size_t)n * 4 + 0], nattr[(size_t)n * 4 + 1]};
        v2f at23 = (v2f){nattr[(size_t)n * 4 + 2], nattr[(size_t)n * 4 + 3]};

        const float* r = nrow[g];
        float scs = 0.f, scv0 = 0.f, scv1 = 0.f, scv2 = 0.f;
#pragma unroll 8
        for (int u = 0; u < 32; ++u) {
            int idx = u * 32 + w;
            v2f ts = at01 * ws_s01[idx] + at23 * ws_s23[idx];
            v2f tv = at01 * ws_v01[idx] + at23 * ws_v23[idx];
            float cs = ts.x + ts.y;
            float cv = tv.x + tv.y;
            scs  += r[u] * cs;
            scv0 += r[32 + u * 3 + 0] * cv;
            scv1 += r[32 + u * 3 + 1] * cv;
            scv2 += r[32 + u * 3 + 2] * cv;
        }
        float* orow = out + (size_t)n * 128;
        orow[w]              = scs  * sc_norm;
        orow[32 + w * 3 + 0] = scv0 * sc_norm;
        orow[32 + w * 3 + 1] = scv1 * sc_norm;
        orow[32 + w * 3 + 2] = scv2 * sc_norm;
    }
}

// ---------------- per-node reduction (no atomics, 1 wave = 1 node) --------

__global__ __launch_bounds__(64) void reduce_kernel(
    const float* __restrict__ fc2, const ushort* __restrict__ sv1,
    const unsigned* __restrict__ recb, const int* __restrict__ rs_end,
    const int* __restrict__ boff, const int* __restrict__ cnt,
    ushort* __restrict__ SVb, int N)
{
    __shared__ float rec[64][20];   // 5.1 KB -> wave-granular scheduling

    int l = threadIdx.x;
    int h = l >> 5;
    int u = l & 31;
    int n = blockIdx.x;

    const float inv_sqrt3 = 0.5773502691896258f;

    v2f f01[8], f23[8];
#pragma unroll
    for (int k = 0; k < 8; ++k) {
        f01[k].x = fc2[k * 128 + u];
        f01[k].y = fc2[k * 128 + 32 + u];
        f23[k].x = fc2[k * 128 + 64 + u];
        f23[k].y = fc2[k * 128 + 96 + u];
    }

    int count = cnt[n];
    int start = rs_end[n] + boff[n >> 10] - count;

    float aS0 = 0.f, aS1 = 0.f;
    float aV0x = 0.f, aV0y = 0.f, aV0z = 0.f;
    float aV1x = 0.f, aV1y = 0.f, aV1z = 0.f;

    for (int j0 = 0; j0 < count; j0 += 64) {
        int nk = count - j0; if (nk > 64) nk = 64;
        // phase 1: coalesced 32B record load + unpack (MLP precomputed)
        if (l < nk) {
            const unsigned* rp = recb + (size_t)(start + j0 + l) * 8;
            uint4 hq = *(const uint4*)rp;
            uint4 aq = *(const uint4*)(rp + 4);
            float* rr = &rec[l][0];
            *(v4f*)rr       = (v4f){bf_lo(hq.x), bf_hi(hq.x), bf_lo(hq.y), bf_hi(hq.y)};
            *(v4f*)(rr + 4) = (v4f){bf_lo(hq.z), bf_hi(hq.z), bf_lo(hq.w), bf_hi(hq.w)};
            *(v4f*)(rr + 8) = (v4f){bf_lo(aq.x), bf_hi(aq.x), bf_lo(aq.y), bf_hi(aq.y)};
            rr[12] = __uint_as_float(aq.z);
        }
        // phase 2: 2 edges/iteration (h picks the edge), branchless 1-deep
        // sv1-row prefetch.
        int pairs = (nk + 1) >> 1;
        int last = nk - 1;
        int s0 = __float_as_int(rec[h <= last ? h : last][12]);
        ushort4 q = *(const ushort4*)(sv1 + (size_t)s0 * 128 + u * 4);
        for (int jj = 0; jj < pairs; ++jj) {
            int slot = jj * 2 + h;
            int nslot = slot + 2 <= last ? slot + 2 : last;
            int sN = __float_as_int(rec[nslot][12]);
            ushort4 qn = *(const ushort4*)(sv1 + (size_t)sN * 128 + u * 4);

            float msk = (slot <= last) ? 1.f : 0.f;
            int slotc = slot <= last ? slot : last;
            const float* rr = &rec[slotc][0];
            v4f H0 = *(const v4f*)rr;
            v4f H1 = *(const v4f*)(rr + 4);
            v4f A  = *(const v4f*)(rr + 8);
            float ss = bf2f(q.x) * msk;
            float vx = bf2f(q.y), vy = bf2f(q.z), vz = bf2f(q.w);

            v2f w01 = H0.x * f01[0] + H0.y * f01[1] + H0.z * f01[2] + H0.w * f01[3]
                    + H1.x * f01[4] + H1.y * f01[5] + H1.z * f01[6] + H1.w * f01[7];
            v2f w23 = H0.x * f23[0] + H0.y * f23[1] + H0.z * f23[2] + H0.w * f23[3]
                    + H1.x * f23[4] + H1.y * f23[5] + H1.z * f23[6] + H1.w * f23[7];

            float dv = (vx * A.y + vy * A.z + vz * A.w) * msk;
            aS0 += w01.x * (ss * A.x);
            aS1 += w23.y * dv;
            float c1 = w01.y * ss;
            aV0x += c1 * A.y; aV0y += c1 * A.z; aV0z += c1 * A.w;
            float c2 = w23.x * A.x * msk;
            aV1x += c2 * vx; aV1y += c2 * vy; aV1z += c2 * vz;
            q = qn;
        }
    }

    aS0  += __shfl_xor(aS0, 32);
    aS1  += __shfl_xor(aS1, 32);
    aV0x += __shfl_xor(aV0x, 32);
    aV0y += __shfl_xor(aV0y, 32);
    aV0z += __shfl_xor(aV0z, 32);
    aV1x += __shfl_xor(aV1x, 32);
    aV1y += __shfl_xor(aV1y, 32);
    aV1z += __shfl_xor(aV1z, 32);

    if (h == 0) {
        // SVb[n][u] packed: {S0,S1'} {V0x,V0y} {V0z,V1x} {V1y,V1z}
        uint4 o;
        o.x = pack_bf(aS0, aS1 * inv_sqrt3);
        o.y = pack_bf(aV0x, aV0y);
        o.z = pack_bf(aV0z, aV1x);
        o.w = pack_bf(aV1y, aV1z);
        *(uint4*)(SVb + (size_t)n * 256 + u * 8) = o;
    }
}

// ---------------- final linear only: out += (S@W2_s, V@W2_v) * l2 ---------
// 1 node per 32-lane group, 18 KB LDS -> 8 blk/CU.

__global__ __launch_bounds__(256) void node_final(
    const ushort* __restrict__ SVb, const float* __restrict__ W2_s,
    const float* __restrict__ W2_v, float* __restrict__ out, int N)
{
    __shared__ uint2 wqb[1024];       // 8 KB
    __shared__ v2f   svtp[8][32][5];  // 10 KB (pad 5: 2-way write alias)

    int g = threadIdx.x >> 5;
    int w = threadIdx.x & 31;

    for (int i = threadIdx.x; i < 1024; i += 256)  // i = u*32+w
        wqb[i] = (uint2){pack_bf(W2_s[i], W2_v[i]),
                         pack_bf(W2_s[i + 1024], W2_v[i + 1024])};
    __syncthreads();

    const float l2 = 0.125f;   // 1/sqrt(64)
    int n = blockIdx.x * 8 + g;
    if (n >= N) return;

    // stage SV row as the 4 pairs the pk_fma loop needs:
    uint4 p = *(const uint4*)(SVb + (size_t)n * 256 + w * 8);
    svtp[g][w][0] = (v2f){bf_lo(p.x), bf_lo(p.z)};   // {S0 , V0z}
    svtp[g][w][1] = (v2f){bf_hi(p.x), bf_hi(p.w)};   // {S1', V1z}
    svtp[g][w][2] = (v2f){bf_lo(p.y), bf_hi(p.y)};   // {V0x, V0y}
    svtp[g][w][3] = (v2f){bf_hi(p.z), bf_lo(p.w)};   // {V1x, V1y}
    // same-wave LDS visibility (32-lane group within one wave)

    v2f sa_va2 = (v2f){0.f, 0.f};
    v2f va01   = (v2f){0.f, 0.f};
#pragma unroll
    for (int u = 0; u < 32; ++u) {
        uint2 qw = wqb[u * 32 + w];
        float w2s_a = bf_lo(qw.x), w2v_a = bf_hi(qw.x);
        float w2s_b = bf_lo(qw.y), w2v_b = bf_hi(qw.y);
        sa_va2 += svtp[g][u][0] * (v2f){w2s_a, w2v_a};  // {sa+=S0*W2s, va2+=V0z*W2v}
        sa_va2 += svtp[g][u][1] * (v2f){w2s_b, w2v_b};
        va01   += svtp[g][u][2] * (v2f){w2v_a, w2v_a};  // {va0+=V0x*W2v, va1+=V0y*W2v}
        va01   += svtp[g][u][3] * (v2f){w2v_b, w2v_b};
    }
    float* orow = out + (size_t)n * 128;
    orow[w]              += sa_va2.x * l2;
    orow[32 + w * 3 + 0] += va01.x   * l2;
    orow[32 + w * 3 + 1] += va01.y   * l2;
    orow[32 + w * 3 + 2] += sa_va2.y * l2;
}

// ---------------- fallback (atomic path, float SV) ----------------

__global__ __launch_bounds__(256) void edge_kernel(
    const float* __restrict__ ea, const float* __restrict__ ee,
    const float* __restrict__ fc1, const float* __restrict__ fc2,
    const ushort* __restrict__ sv1, const int* __restrict__ eidx,
    float* __restrict__ SV, int E)
{
    long long tid = (long long)blockIdx.x * 256 + threadIdx.x;
    int e = (int)(tid >> 5);
    int u = (int)(tid & 31);
    if (e >= E) return;
    const float rs8 = 0.35355339059327373f;
    const float inv_sqrt3 = 0.5773502691896258f;
    float ev[8];
#pragma unroll
    for (int i = 0; i < 8; ++i) ev[i] = ee[(size_t)e * 8 + i];
    float h[8];
#pragma unroll
    for (int k = 0; k < 8; ++k) {
        float t = 0.f;
#pragma unroll
        for (int i = 0; i < 8; ++i) t += ev[i] * fc1[i * 8 + k];
        t *= rs8;
        h[k] = t / (1.f + expf(-t));
    }
    float w0 = 0.f, w1 = 0.f, w2 = 0.f, w3 = 0.f;
#pragma unroll
    for (int k = 0; k < 8; ++k) {
        const float* f2 = fc2 + k * 128;
        float hk = h[k];
        w0 += hk * f2[u];
        w1 += hk * f2[32 + u];
        w2 += hk * f2[64 + u];
        w3 += hk * f2[96 + u];
    }
    w0 *= rs8; w1 *= rs8; w2 *= rs8; w3 *= rs8;
    int dst = eidx[e];
    int src = eidx[E + e];
    float a0 = ea[(size_t)e * 4 + 0];
    float ax = ea[(size_t)e * 4 + 1];
    float ay = ea[(size_t)e * 4 + 2];
    float az = ea[(size_t)e * 4 + 3];
    ushort4 q = *(const ushort4*)(sv1 + (size_t)src * 128 + u * 4);
    float ss = bf2f(q.x), vx = bf2f(q.y), vy = bf2f(q.z), vz = bf2f(q.w);
    float dv = vx * ax + vy * ay + vz * az;
    float* o = SV + (size_t)dst * 256 + u * 8;
    atomicAdd(o + 0, w0 * ss * a0);
    atomicAdd(o + 1, w3 * dv * inv_sqrt3);
    float c1 = w1 * ss;
    atomicAdd(o + 2, c1 * ax);
    atomicAdd(o + 3, c1 * ay);
    atomicAdd(o + 4, c1 * az);
    float c2 = w2 * a0;
    atomicAdd(o + 5, c2 * vx);
    atomicAdd(o + 6, c2 * vy);
    atomicAdd(o + 7, c2 * vz);
}

// fallback final: linear from f32 SV, += onto the skip already in out
__global__ __launch_bounds__(256) void node_final_f32(
    const float* __restrict__ SV, const float* __restrict__ W2_s,
    const float* __restrict__ W2_v, float* __restrict__ out, int N)
{
    __shared__ float wq[4096];
    __shared__ float svt[8][8][32];

    int g = threadIdx.x >> 5;
    int w = threadIdx.x & 31;

    for (int i = threadIdx.x; i < 1024; i += 256)
        *(float4*)&wq[i * 4] = make_float4(W2_s[i], W2_s[i + 1024],
                                           W2_v[i], W2_v[i + 1024]);
    __syncthreads();

    const float l2 = 0.125f;

    for (int t = 0; t < 4; ++t) {
        int n = blockIdx.x * 32 + g * 4 + t;
        if (n >= N) continue;
        const float* svp = SV + (size_t)n * 256 + w * 8;
        float4 p0 = *(const float4*)svp;
        float4 p1 = *(const float4*)(svp + 4);
        svt[g][0][w] = p0.x; svt[g][1][w] = p0.y;
        svt[g][2][w] = p0.z; svt[g][3][w] = p0.w;
        svt[g][4][w] = p1.x; svt[g][5][w] = p1.y;
        svt[g][6][w] = p1.z; svt[g][7][w] = p1.w;

        float sa = 0.f, va0 = 0.f, va1 = 0.f, va2 = 0.f;
#pragma unroll
        for (int u = 0; u < 32; ++u) {
            float4 qw = *(const float4*)&wq[(u * 32 + w) * 4];
            sa  += svt[g][0][u] * qw.x + svt[g][1][u] * qw.y;
            va0 += svt[g][2][u] * qw.z + svt[g][5][u] * qw.w;
            va1 += svt[g][3][u] * qw.z + svt[g][6][u] * qw.w;
            va2 += svt[g][4][u] * qw.z + svt[g][7][u] * qw.w;
        }
        float* orow = out + (size_t)n * 128;
        orow[w]              += sa  * l2;
        orow[32 + w * 3 + 0] += va0 * l2;
        orow[32 + w * 3 + 1] += va1 * l2;
        orow[32 + w * 3 + 2] += va2 * l2;
    }
}

extern "C" void kernel_launch(void* const* d_in, const int* in_sizes, int n_in,
                              void* d_out, int out_size, void* d_ws, size_t ws_size,
                              hipStream_t stream) {
    const float* nf    = (const float*)d_in[0];
    const float* nattr = (const float*)d_in[1];
    const float* ea    = (const float*)d_in[2];
    const float* ee    = (const float*)d_in[3];
    const float* W1_s  = (const float*)d_in[4];
    const float* W1_v  = (const float*)d_in[5];
    const float* fc1   = (const float*)d_in[6];
    const float* fc2   = (const float*)d_in[7];
    const float* W2_s  = (const float*)d_in[8];
    const float* W2_v  = (const float*)d_in[9];
    const float* Wsc_s = (const float*)d_in[10];
    const float* Wsc_v = (const float*)d_in[11];
    const int*   eidx  = (const int*)d_in[12];

    int N = in_sizes[0] / 128;
    int E = in_sizes[12] / 2;

    float* ws = (float*)d_ws;
    // main-path layout (float units)
    ushort* sv1 = (ushort*)ws;                         // N*128 ushorts (N*64 f)
    ushort* SVb = (ushort*)(ws + (size_t)N * 64);      // N*256 ushorts (N*128 f)
    unsigned* recb = (unsigned*)(ws + (size_t)N * 192); // E*8 uints
    int* cnt  = (int*)(ws + (size_t)N * 192 + (size_t)E * 8); // N
    int* rs   = cnt + N;                               // N
    int* bsum = rs + N;                                // 64
    int* boff = bsum + 64;                             // 64

    size_t needed = ((size_t)N * 194 + (size_t)E * 8 + 128) * 4;

    int nb_node = (N + 7) / 8;
    int nbE = (E + 255) / 256;

    if (ws_size >= needed) {
        hipMemsetAsync(cnt, 0, (size_t)N * sizeof(int), stream);
        node_prep<<<nb_node, 256, 0, stream>>>(nf, W1_s, W1_v, eidx, cnt, sv1, N, E);
        int nbS = (N + 1023) / 1024;
        scan_a<<<nbS, 1024, 0, stream>>>(cnt, rs, bsum, N);
        scan_b<<<1, 64, 0, stream>>>(bsum, boff, nbS);
        // fused: scatter_build (blocks < nbE) + skip (blocks >= nbE)
        scatter_build_skip<<<nbE + nb_node, 256, 0, stream>>>(
            ea, ee, fc1, eidx, rs, boff, recb, E, nbE,
            nf, nattr, Wsc_s, Wsc_v, (float*)d_out, N);
        reduce_kernel<<<N, 64, 0, stream>>>(fc2, sv1, recb, rs, boff, cnt,
                                            SVb, N);
        node_final<<<nb_node, 256, 0, stream>>>(SVb, W2_s, W2_v,
                                                (float*)d_out, N);
    } else {
        // fallback: atomic path with float SV; skip via fused kernel (nbE=0)
        float* SVf = ws + (size_t)N * 64;           // N*256 floats
        int* cnt_f = (int*)(SVf + (size_t)N * 256); // N
        hipMemsetAsync(SVf, 0, (size_t)N * 256 * sizeof(float), stream);
        hipMemsetAsync(cnt_f, 0, (size_t)N * sizeof(int), stream);
        node_prep<<<nb_node, 256, 0, stream>>>(nf, W1_s, W1_v, eidx, cnt_f, sv1, N, E);
        long long tot = (long long)E * 32;
        int nb_edge = (int)((tot + 255) / 256);
        edge_kernel<<<nb_edge, 256, 0, stream>>>(ea, ee, fc1, fc2, sv1, eidx, SVf, E);
        scatter_build_skip<<<nb_node, 256, 0, stream>>>(
            ea, ee, fc1, eidx, (int*)cnt_f, (const int*)cnt_f, (unsigned*)cnt_f,
            0, 0, nf, nattr, Wsc_s, Wsc_v, (float*)d_out, N);
        int nb_final_f = (N + 31) / 32;
        node_final_f32<<<nb_final_f, 256, 0, stream>>>(SVf, W2_s, W2_v,
                                                       (float*)d_out, N);
    }
}

// Round 20
// 220.993 us; speedup vs baseline: 1.2794x; 1.0210x over previous
//
#include <hip/hip_runtime.h>
#include <math.h>

// ---------------------------------------------------------------------------
// InteractionBlock: gather -> per-edge tensor-product -> scatter -> linear
// N=50000 nodes, E=800000 edges, MUL=32.
//
// Round-19 = R18 with the fused kernel's LDS cut below the occupancy knee:
//  * scatter_build_skip: skip side uses bf16-packed Wsc (two uint2 arrays,
//    8+8 KB) + nrow 4 KB = 20 KB total -> 8 blk/CU (full wave cap). R18's
//    36 KB capped the latency-bound scatter blocks at 4 blk/CU (87us fused
//    > 65us serial). bf16 Wsc proven at absmax 0.03125 in R12-R14.
//  * node_prep, scans, reduce (1 wave/node, 32B records): exact R14.
//  * node_final: lean linear-only 18 KB, out += (proven R17/R18).
//
// ws layout (float units):
//   sv1[N*64] | SVb[N*128] | recb[E*8] | cnt[N] | rs[N] | bsum[64] | boff[64]
// ---------------------------------------------------------------------------

typedef float  v2f __attribute__((ext_vector_type(2)));
typedef float  v4f __attribute__((ext_vector_type(4)));

__device__ __forceinline__ unsigned short f2bf(float x) {
    unsigned u = __float_as_uint(x);
    u += 0x7FFFu + ((u >> 16) & 1u);   // RNE
    return (unsigned short)(u >> 16);
}
__device__ __forceinline__ float bf2f(unsigned short h) {
    return __uint_as_float(((unsigned)h) << 16);
}
__device__ __forceinline__ unsigned pack_bf(float lo, float hi) {
    unsigned ul = __float_as_uint(lo);
    ul = (ul + (0x7FFFu + ((ul >> 16) & 1u))) >> 16;
    unsigned uh = __float_as_uint(hi);
    uh = (uh + (0x7FFFu + ((uh >> 16) & 1u))) & 0xFFFF0000u;
    return ul | uh;
}
__device__ __forceinline__ float bf_lo(unsigned p) { return __uint_as_float(p << 16); }
__device__ __forceinline__ float bf_hi(unsigned p) { return __uint_as_float(p & 0xFFFF0000u); }

__global__ __launch_bounds__(256) void node_prep(
    const float* __restrict__ nf, const float* __restrict__ W1_s,
    const float* __restrict__ W1_v, const int* __restrict__ eidx,
    int* __restrict__ cnt, ushort* __restrict__ sv1, int N, int E)
{
    __shared__ float w1s[1024];
    __shared__ float w1v[1024];
    __shared__ float nrow[8][128];

    // folded histogram of dst
    for (long long e = (long long)blockIdx.x * 256 + threadIdx.x; e < E;
         e += (long long)gridDim.x * 256)
        atomicAdd(cnt + eidx[(int)e], 1);

    int g = threadIdx.x >> 5;
    int w = threadIdx.x & 31;
    int n = blockIdx.x * 8 + g;

    for (int i = threadIdx.x; i < 1024; i += 256) {
        w1s[i] = W1_s[i];
        w1v[i] = W1_v[i];
    }
    if (n < N) {
        float4 q = *(const float4*)(nf + (size_t)n * 128 + w * 4);
        *(float4*)&nrow[g][w * 4] = q;
    }
    __syncthreads();
    if (n >= N) return;

    const float l1 = 0.17677669529663687f; // 1/sqrt(32)
    const float* r = nrow[g];
    float ss = 0.f, vx = 0.f, vy = 0.f, vz = 0.f;
#pragma unroll 8
    for (int u = 0; u < 32; ++u) {
        float ws = w1s[u * 32 + w];
        float wv = w1v[u * 32 + w];
        ss += r[u] * ws;
        vx += r[32 + u * 3 + 0] * wv;
        vy += r[32 + u * 3 + 1] * wv;
        vz += r[32 + u * 3 + 2] * wv;
    }
    ushort4 o;
    o.x = f2bf(ss * l1); o.y = f2bf(vx * l1);
    o.z = f2bf(vy * l1); o.w = f2bf(vz * l1);
    *(ushort4*)(sv1 + (size_t)n * 128 + w * 4) = o;
}

// ---------------- CSR build ----------------

__global__ __launch_bounds__(1024) void scan_a(
    const int* __restrict__ cnt, int* __restrict__ rs,
    int* __restrict__ bsum, int N)
{
    int i = blockIdx.x * 1024 + threadIdx.x;
    int lane = threadIdx.x & 63;
    int wid = threadIdx.x >> 6;
    int v = (i < N) ? cnt[i] : 0;
    int incl = v;
#pragma unroll
    for (int d = 1; d < 64; d <<= 1) {
        int t = __shfl_up(incl, d);
        if (lane >= d) incl += t;
    }
    __shared__ int wtot[16];
    __shared__ int woff[16];
    if (lane == 63) wtot[wid] = incl;
    __syncthreads();
    if (wid == 0) {
        int t = (lane < 16) ? wtot[lane] : 0;
        int s = t;
#pragma unroll
        for (int d = 1; d < 16; d <<= 1) {
            int q = __shfl_up(s, d);
            if (lane >= d) s += q;
        }
        if (lane < 16) woff[lane] = s - t;
        if (lane == 15) bsum[blockIdx.x] = s;
    }
    __syncthreads();
    if (i < N) rs[i] = woff[wid] + incl - v;   // block-local exclusive prefix
}

__global__ __launch_bounds__(64) void scan_b(
    const int* __restrict__ bsum, int* __restrict__ boff, int nb)
{
    int lane = threadIdx.x;
    int carry = 0;
    for (int base = 0; base < nb; base += 64) {
        int i = base + lane;
        int v = (i < nb) ? bsum[i] : 0;
        int s = v;
#pragma unroll
        for (int d = 1; d < 64; d <<= 1) {
            int t = __shfl_up(s, d);
            if (lane >= d) s += t;
        }
        if (i < nb) boff[i] = carry + s - v;
        carry += __shfl(s, 63);
    }
}

// ---------------- fused scatter_build + skip (heterogeneous blocks) -------
// blocks < nbE: scatter+MLP -> 32B record at dst-sorted position.
// blocks >= nbE: skip einsum (bf16 Wsc pairs in LDS) -> out = skip.
// 20 KB LDS total -> 8 blk/CU: scatter keeps full residency (R18's 36 KB
// choked it at 4 blk/CU), skip waves fill scatter's latency bubbles.

__global__ __launch_bounds__(256) void scatter_build_skip(
    const float* __restrict__ ea, const float* __restrict__ ee,
    const float* __restrict__ fc1, const int* __restrict__ eidx,
    int* __restrict__ rs, const int* __restrict__ boff,
    unsigned* __restrict__ recb, int E, int nbE,
    const float* __restrict__ nf, const float* __restrict__ nattr,
    const float* __restrict__ Wsc_s, const float* __restrict__ Wsc_v,
    float* __restrict__ out, int N)
{
    __shared__ uint2 ws_sb[1024];    // 8 KB {pack(ws0,ws1), pack(ws2,ws3)}
    __shared__ uint2 ws_vb[1024];    // 8 KB
    __shared__ float nrow[8][128];   // 4 KB -> 20 KB total, 8 blk/CU

    if ((int)blockIdx.x < nbE) {
        // ---- scatter_build ----
        int e = blockIdx.x * 256 + threadIdx.x;
        if (e >= E) return;
        const float rs8 = 0.35355339059327373f;   // 1/sqrt(8)

        int d = eidx[e];
        int src = eidx[E + e];
        int p = atomicAdd(rs + d, 1) + boff[d >> 10];

        const float* eep = ee + (size_t)e * 8;
        v4f e0 = *(const v4f*)eep;
        v4f e1 = *(const v4f*)(eep + 4);
        float ev[8] = {e0.x, e0.y, e0.z, e0.w, e1.x, e1.y, e1.z, e1.w};
        float hh[8];
#pragma unroll
        for (int k = 0; k < 8; ++k) {
            float t = 0.f;
#pragma unroll
            for (int i = 0; i < 8; ++i) t += ev[i] * fc1[i * 8 + k];
            t *= rs8;
            hh[k] = t * __builtin_amdgcn_rcpf(1.f + __expf(-t)) * rs8;
        }
        uint4 hp;
        hp.x = pack_bf(hh[0], hh[1]);
        hp.y = pack_bf(hh[2], hh[3]);
        hp.z = pack_bf(hh[4], hh[5]);
        hp.w = pack_bf(hh[6], hh[7]);
        v4f a = *(const v4f*)(ea + (size_t)e * 4);
        uint4 t2;
        t2.x = pack_bf(a.x, a.y);
        t2.y = pack_bf(a.z, a.w);
        t2.z = (unsigned)src;
        t2.w = 0u;
        unsigned* rp = recb + (size_t)p * 8;
        *(uint4*)rp       = hp;
        *(uint4*)(rp + 4) = t2;
    } else {
        // ---- skip connection: out = einsum(nf, nattr, Wsc) * sc_norm ----
        int b = blockIdx.x - nbE;
        int g = threadIdx.x >> 5;
        int w = threadIdx.x & 31;

        for (int i = threadIdx.x; i < 1024; i += 256) {
            int uu = i >> 5, ww = i & 31;
            const float* ps = Wsc_s + (size_t)uu * 128 + ww;
            const float* pv = Wsc_v + (size_t)uu * 128 + ww;
            ws_sb[i] = (uint2){pack_bf(ps[0], ps[32]), pack_bf(ps[64], ps[96])};
            ws_vb[i] = (uint2){pack_bf(pv[0], pv[32]), pack_bf(pv[64], pv[96])};
        }
        int n = b * 8 + g;
        if (n < N) {
            float4 q = *(const float4*)(nf + (size_t)n * 128 + w * 4);
            *(float4*)&nrow[g][w * 4] = q;
        }
        __syncthreads();
        if (n >= N) return;

        const float sc_norm = 0.08838834764831843f; // 1/sqrt(128)
        float at0 = nattr[(size_t)n * 4 + 0];
        float at1 = nattr[(size_t)n * 4 + 1];
        float at2 = nattr[(size_t)n * 4 + 2];
        float at3 = nattr[(size_t)n * 4 + 3];

        const float* r = nrow[g];
        float scs = 0.f, scv0 = 0.f, scv1 = 0.f, scv2 = 0.f;
#pragma unroll 8
        for (int u = 0; u < 32; ++u) {
            int idx = u * 32 + w;
            uint2 wsq = ws_sb[idx];
            uint2 wvq = ws_vb[idx];
            float cs = at0 * bf_lo(wsq.x) + at1 * bf_hi(wsq.x)
                     + at2 * bf_lo(wsq.y) + at3 * bf_hi(wsq.y);
            float cv = at0 * bf_lo(wvq.x) + at1 * bf_hi(wvq.x)
                     + at2 * bf_lo(wvq.y) + at3 * bf_hi(wvq.y);
            scs  += r[u] * cs;
            scv0 += r[32 + u * 3 + 0] * cv;
            scv1 += r[32 + u * 3 + 1] * cv;
            scv2 += r[32 + u * 3 + 2] * cv;
        }
        float* orow = out + (size_t)n * 128;
        orow[w]              = scs  * sc_norm;
        orow[32 + w * 3 + 0] = scv0 * sc_norm;
        orow[32 + w * 3 + 1] = scv1 * sc_norm;
        orow[32 + w * 3 + 2] = scv2 * sc_norm;
    }
}

// ---------------- per-node reduction (no atomics, 1 wave = 1 node) --------

__global__ __launch_bounds__(64) void reduce_kernel(
    const float* __restrict__ fc2, const ushort* __restrict__ sv1,
    const unsigned* __restrict__ recb, const int* __restrict__ rs_end,
    const int* __restrict__ boff, const int* __restrict__ cnt,
    ushort* __restrict__ SVb, int N)
{
    __shared__ float rec[64][20];   // 5.1 KB -> wave-granular scheduling

    int l = threadIdx.x;
    int h = l >> 5;
    int u = l & 31;
    int n = blockIdx.x;

    const float inv_sqrt3 = 0.5773502691896258f;

    v2f f01[8], f23[8];
#pragma unroll
    for (int k = 0; k < 8; ++k) {
        f01[k].x = fc2[k * 128 + u];
        f01[k].y = fc2[k * 128 + 32 + u];
        f23[k].x = fc2[k * 128 + 64 + u];
        f23[k].y = fc2[k * 128 + 96 + u];
    }

    int count = cnt[n];
    int start = rs_end[n] + boff[n >> 10] - count;

    float aS0 = 0.f, aS1 = 0.f;
    float aV0x = 0.f, aV0y = 0.f, aV0z = 0.f;
    float aV1x = 0.f, aV1y = 0.f, aV1z = 0.f;

    for (int j0 = 0; j0 < count; j0 += 64) {
        int nk = count - j0; if (nk > 64) nk = 64;
        // phase 1: coalesced 32B record load + unpack (MLP precomputed)
        if (l < nk) {
            const unsigned* rp = recb + (size_t)(start + j0 + l) * 8;
            uint4 hq = *(const uint4*)rp;
            uint4 aq = *(const uint4*)(rp + 4);
            float* rr = &rec[l][0];
            *(v4f*)rr       = (v4f){bf_lo(hq.x), bf_hi(hq.x), bf_lo(hq.y), bf_hi(hq.y)};
            *(v4f*)(rr + 4) = (v4f){bf_lo(hq.z), bf_hi(hq.z), bf_lo(hq.w), bf_hi(hq.w)};
            *(v4f*)(rr + 8) = (v4f){bf_lo(aq.x), bf_hi(aq.x), bf_lo(aq.y), bf_hi(aq.y)};
            rr[12] = __uint_as_float(aq.z);
        }
        // phase 2: 2 edges/iteration (h picks the edge), branchless 1-deep
        // sv1-row prefetch.
        int pairs = (nk + 1) >> 1;
        int last = nk - 1;
        int s0 = __float_as_int(rec[h <= last ? h : last][12]);
        ushort4 q = *(const ushort4*)(sv1 + (size_t)s0 * 128 + u * 4);
        for (int jj = 0; jj < pairs; ++jj) {
            int slot = jj * 2 + h;
            int nslot = slot + 2 <= last ? slot + 2 : last;
            int sN = __float_as_int(rec[nslot][12]);
            ushort4 qn = *(const ushort4*)(sv1 + (size_t)sN * 128 + u * 4);

            float msk = (slot <= last) ? 1.f : 0.f;
            int slotc = slot <= last ? slot : last;
            const float* rr = &rec[slotc][0];
            v4f H0 = *(const v4f*)rr;
            v4f H1 = *(const v4f*)(rr + 4);
            v4f A  = *(const v4f*)(rr + 8);
            float ss = bf2f(q.x) * msk;
            float vx = bf2f(q.y), vy = bf2f(q.z), vz = bf2f(q.w);

            v2f w01 = H0.x * f01[0] + H0.y * f01[1] + H0.z * f01[2] + H0.w * f01[3]
                    + H1.x * f01[4] + H1.y * f01[5] + H1.z * f01[6] + H1.w * f01[7];
            v2f w23 = H0.x * f23[0] + H0.y * f23[1] + H0.z * f23[2] + H0.w * f23[3]
                    + H1.x * f23[4] + H1.y * f23[5] + H1.z * f23[6] + H1.w * f23[7];

            float dv = (vx * A.y + vy * A.z + vz * A.w) * msk;
            aS0 += w01.x * (ss * A.x);
            aS1 += w23.y * dv;
            float c1 = w01.y * ss;
            aV0x += c1 * A.y; aV0y += c1 * A.z; aV0z += c1 * A.w;
            float c2 = w23.x * A.x * msk;
            aV1x += c2 * vx; aV1y += c2 * vy; aV1z += c2 * vz;
            q = qn;
        }
    }

    aS0  += __shfl_xor(aS0, 32);
    aS1  += __shfl_xor(aS1, 32);
    aV0x += __shfl_xor(aV0x, 32);
    aV0y += __shfl_xor(aV0y, 32);
    aV0z += __shfl_xor(aV0z, 32);
    aV1x += __shfl_xor(aV1x, 32);
    aV1y += __shfl_xor(aV1y, 32);
    aV1z += __shfl_xor(aV1z, 32);

    if (h == 0) {
        // SVb[n][u] packed: {S0,S1'} {V0x,V0y} {V0z,V1x} {V1y,V1z}
        uint4 o;
        o.x = pack_bf(aS0, aS1 * inv_sqrt3);
        o.y = pack_bf(aV0x, aV0y);
        o.z = pack_bf(aV0z, aV1x);
        o.w = pack_bf(aV1y, aV1z);
        *(uint4*)(SVb + (size_t)n * 256 + u * 8) = o;
    }
}

// ---------------- final linear only: out += (S@W2_s, V@W2_v) * l2 ---------
// 1 node per 32-lane group, 18 KB LDS -> 8 blk/CU.

__global__ __launch_bounds__(256) void node_final(
    const ushort* __restrict__ SVb, const float* __restrict__ W2_s,
    const float* __restrict__ W2_v, float* __restrict__ out, int N)
{
    __shared__ uint2 wqb[1024];       // 8 KB
    __shared__ v2f   svtp[8][32][5];  // 10 KB (pad 5: 2-way write alias)

    int g = threadIdx.x >> 5;
    int w = threadIdx.x & 31;

    for (int i = threadIdx.x; i < 1024; i += 256)  // i = u*32+w
        wqb[i] = (uint2){pack_bf(W2_s[i], W2_v[i]),
                         pack_bf(W2_s[i + 1024], W2_v[i + 1024])};
    __syncthreads();

    const float l2 = 0.125f;   // 1/sqrt(64)
    int n = blockIdx.x * 8 + g;
    if (n >= N) return;

    // stage SV row as the 4 pairs the pk_fma loop needs:
    uint4 p = *(const uint4*)(SVb + (size_t)n * 256 + w * 8);
    svtp[g][w][0] = (v2f){bf_lo(p.x), bf_lo(p.z)};   // {S0 , V0z}
    svtp[g][w][1] = (v2f){bf_hi(p.x), bf_hi(p.w)};   // {S1', V1z}
    svtp[g][w][2] = (v2f){bf_lo(p.y), bf_hi(p.y)};   // {V0x, V0y}
    svtp[g][w][3] = (v2f){bf_hi(p.z), bf_lo(p.w)};   // {V1x, V1y}
    // same-wave LDS visibility (32-lane group within one wave)

    v2f sa_va2 = (v2f){0.f, 0.f};
    v2f va01   = (v2f){0.f, 0.f};
#pragma unroll
    for (int u = 0; u < 32; ++u) {
        uint2 qw = wqb[u * 32 + w];
        float w2s_a = bf_lo(qw.x), w2v_a = bf_hi(qw.x);
        float w2s_b = bf_lo(qw.y), w2v_b = bf_hi(qw.y);
        sa_va2 += svtp[g][u][0] * (v2f){w2s_a, w2v_a};  // {sa+=S0*W2s, va2+=V0z*W2v}
        sa_va2 += svtp[g][u][1] * (v2f){w2s_b, w2v_b};
        va01   += svtp[g][u][2] * (v2f){w2v_a, w2v_a};  // {va0+=V0x*W2v, va1+=V0y*W2v}
        va01   += svtp[g][u][3] * (v2f){w2v_b, w2v_b};
    }
    float* orow = out + (size_t)n * 128;
    orow[w]              += sa_va2.x * l2;
    orow[32 + w * 3 + 0] += va01.x   * l2;
    orow[32 + w * 3 + 1] += va01.y   * l2;
    orow[32 + w * 3 + 2] += sa_va2.y * l2;
}

// ---------------- fallback (atomic path, float SV) ----------------

__global__ __launch_bounds__(256) void edge_kernel(
    const float* __restrict__ ea, const float* __restrict__ ee,
    const float* __restrict__ fc1, const float* __restrict__ fc2,
    const ushort* __restrict__ sv1, const int* __restrict__ eidx,
    float* __restrict__ SV, int E)
{
    long long tid = (long long)blockIdx.x * 256 + threadIdx.x;
    int e = (int)(tid >> 5);
    int u = (int)(tid & 31);
    if (e >= E) return;
    const float rs8 = 0.35355339059327373f;
    const float inv_sqrt3 = 0.5773502691896258f;
    float ev[8];
#pragma unroll
    for (int i = 0; i < 8; ++i) ev[i] = ee[(size_t)e * 8 + i];
    float h[8];
#pragma unroll
    for (int k = 0; k < 8; ++k) {
        float t = 0.f;
#pragma unroll
        for (int i = 0; i < 8; ++i) t += ev[i] * fc1[i * 8 + k];
        t *= rs8;
        h[k] = t / (1.f + expf(-t));
    }
    float w0 = 0.f, w1 = 0.f, w2 = 0.f, w3 = 0.f;
#pragma unroll
    for (int k = 0; k < 8; ++k) {
        const float* f2 = fc2 + k * 128;
        float hk = h[k];
        w0 += hk * f2[u];
        w1 += hk * f2[32 + u];
        w2 += hk * f2[64 + u];
        w3 += hk * f2[96 + u];
    }
    w0 *= rs8; w1 *= rs8; w2 *= rs8; w3 *= rs8;
    int dst = eidx[e];
    int src = eidx[E + e];
    float a0 = ea[(size_t)e * 4 + 0];
    float ax = ea[(size_t)e * 4 + 1];
    float ay = ea[(size_t)e * 4 + 2];
    float az = ea[(size_t)e * 4 + 3];
    ushort4 q = *(const ushort4*)(sv1 + (size_t)src * 128 + u * 4);
    float ss = bf2f(q.x), vx = bf2f(q.y), vy = bf2f(q.z), vz = bf2f(q.w);
    float dv = vx * ax + vy * ay + vz * az;
    float* o = SV + (size_t)dst * 256 + u * 8;
    atomicAdd(o + 0, w0 * ss * a0);
    atomicAdd(o + 1, w3 * dv * inv_sqrt3);
    float c1 = w1 * ss;
    atomicAdd(o + 2, c1 * ax);
    atomicAdd(o + 3, c1 * ay);
    atomicAdd(o + 4, c1 * az);
    float c2 = w2 * a0;
    atomicAdd(o + 5, c2 * vx);
    atomicAdd(o + 6, c2 * vy);
    atomicAdd(o + 7, c2 * vz);
}

// fallback final: linear from f32 SV, += onto the skip already in out
__global__ __launch_bounds__(256) void node_final_f32(
    const float* __restrict__ SV, const float* __restrict__ W2_s,
    const float* __restrict__ W2_v, float* __restrict__ out, int N)
{
    __shared__ float wq[4096];
    __shared__ float svt[8][8][32];

    int g = threadIdx.x >> 5;
    int w = threadIdx.x & 31;

    for (int i = threadIdx.x; i < 1024; i += 256)
        *(float4*)&wq[i * 4] = make_float4(W2_s[i], W2_s[i + 1024],
                                           W2_v[i], W2_v[i + 1024]);
    __syncthreads();

    const float l2 = 0.125f;

    for (int t = 0; t < 4; ++t) {
        int n = blockIdx.x * 32 + g * 4 + t;
        if (n >= N) continue;
        const float* svp = SV + (size_t)n * 256 + w * 8;
        float4 p0 = *(const float4*)svp;
        float4 p1 = *(const float4*)(svp + 4);
        svt[g][0][w] = p0.x; svt[g][1][w] = p0.y;
        svt[g][2][w] = p0.z; svt[g][3][w] = p0.w;
        svt[g][4][w] = p1.x; svt[g][5][w] = p1.y;
        svt[g][6][w] = p1.z; svt[g][7][w] = p1.w;

        float sa = 0.f, va0 = 0.f, va1 = 0.f, va2 = 0.f;
#pragma unroll
        for (int u = 0; u < 32; ++u) {
            float4 qw = *(const float4*)&wq[(u * 32 + w) * 4];
            sa  += svt[g][0][u] * qw.x + svt[g][1][u] * qw.y;
            va0 += svt[g][2][u] * qw.z + svt[g][5][u] * qw.w;
            va1 += svt[g][3][u] * qw.z + svt[g][6][u] * qw.w;
            va2 += svt[g][4][u] * qw.z + svt[g][7][u] * qw.w;
        }
        float* orow = out + (size_t)n * 128;
        orow[w]              += sa  * l2;
        orow[32 + w * 3 + 0] += va0 * l2;
        orow[32 + w * 3 + 1] += va1 * l2;
        orow[32 + w * 3 + 2] += va2 * l2;
    }
}

extern "C" void kernel_launch(void* const* d_in, const int* in_sizes, int n_in,
                              void* d_out, int out_size, void* d_ws, size_t ws_size,
                              hipStream_t stream) {
    const float* nf    = (const float*)d_in[0];
    const float* nattr = (const float*)d_in[1];
    const float* ea    = (const float*)d_in[2];
    const float* ee    = (const float*)d_in[3];
    const float* W1_s  = (const float*)d_in[4];
    const float* W1_v  = (const float*)d_in[5];
    const float* fc1   = (const float*)d_in[6];
    const float* fc2   = (const float*)d_in[7];
    const float* W2_s  = (const float*)d_in[8];
    const float* W2_v  = (const float*)d_in[9];
    const float* Wsc_s = (const float*)d_in[10];
    const float* Wsc_v = (const float*)d_in[11];
    const int*   eidx  = (const int*)d_in[12];

    int N = in_sizes[0] / 128;
    int E = in_sizes[12] / 2;

    float* ws = (float*)d_ws;
    // main-path layout (float units)
    ushort* sv1 = (ushort*)ws;                         // N*128 ushorts (N*64 f)
    ushort* SVb = (ushort*)(ws + (size_t)N * 64);      // N*256 ushorts (N*128 f)
    unsigned* recb = (unsigned*)(ws + (size_t)N * 192); // E*8 uints
    int* cnt  = (int*)(ws + (size_t)N * 192 + (size_t)E * 8); // N
    int* rs   = cnt + N;                               // N
    int* bsum = rs + N;                                // 64
    int* boff = bsum + 64;                             // 64

    size_t needed = ((size_t)N * 194 + (size_t)E * 8 + 128) * 4;

    int nb_node = (N + 7) / 8;
    int nbE = (E + 255) / 256;

    if (ws_size >= needed) {
        hipMemsetAsync(cnt, 0, (size_t)N * sizeof(int), stream);
        node_prep<<<nb_node, 256, 0, stream>>>(nf, W1_s, W1_v, eidx, cnt, sv1, N, E);
        int nbS = (N + 1023) / 1024;
        scan_a<<<nbS, 1024, 0, stream>>>(cnt, rs, bsum, N);
        scan_b<<<1, 64, 0, stream>>>(bsum, boff, nbS);
        // fused: scatter_build (blocks < nbE) + skip (blocks >= nbE), 20KB LDS
        scatter_build_skip<<<nbE + nb_node, 256, 0, stream>>>(
            ea, ee, fc1, eidx, rs, boff, recb, E, nbE,
            nf, nattr, Wsc_s, Wsc_v, (float*)d_out, N);
        reduce_kernel<<<N, 64, 0, stream>>>(fc2, sv1, recb, rs, boff, cnt,
                                            SVb, N);
        node_final<<<nb_node, 256, 0, stream>>>(SVb, W2_s, W2_v,
                                                (float*)d_out, N);
    } else {
        // fallback: atomic path with float SV; skip via fused kernel (nbE=0)
        float* SVf = ws + (size_t)N * 64;           // N*256 floats
        int* cnt_f = (int*)(SVf + (size_t)N * 256); // N
        hipMemsetAsync(SVf, 0, (size_t)N * 256 * sizeof(float), stream);
        hipMemsetAsync(cnt_f, 0, (size_t)N * sizeof(int), stream);
        node_prep<<<nb_node, 256, 0, stream>>>(nf, W1_s, W1_v, eidx, cnt_f, sv1, N, E);
        long long tot = (long long)E * 32;
        int nb_edge = (int)((tot + 255) / 256);
        edge_kernel<<<nb_edge, 256, 0, stream>>>(ea, ee, fc1, fc2, sv1, eidx, SVf, E);
        scatter_build_skip<<<nb_node, 256, 0, stream>>>(
            ea, ee, fc1, eidx, (int*)cnt_f, (const int*)cnt_f, (unsigned*)cnt_f,
            0, 0, nf, nattr, Wsc_s, Wsc_v, (float*)d_out, N);
        int nb_final_f = (N + 31) / 32;
        node_final_f32<<<nb_final_f, 256, 0, stream>>>(SVf, W2_s, W2_v,
                                                       (float*)d_out, N);
    }
}

// Round 21
// 213.892 us; speedup vs baseline: 1.3218x; 1.0332x over previous
//
#include <hip/hip_runtime.h>
#include <math.h>

// ---------------------------------------------------------------------------
// InteractionBlock: gather -> per-edge tensor-product -> scatter -> linear
// N=50000 nodes, E=800000 edges, MUL=32.
//
// FINAL (= Round-14, measured 216.0 us, best of 20 rounds):
//  * scatter_build fused (MLP in the sequential pass) with ONE 32B record
//    {h8,a4,src,pad} = 2 adjacent b128 stores at the dst-sorted position.
//  * reduce: block = 64 = 1 wave = 1 node (grid = N), rec 5.1KB/block,
//    wave-granular scheduling; coalesced record loads; pk_fma chains;
//    branchless 1-deep sv1 prefetch; bf16 sv1 + SVb.
//  * node_final fused (linear + skip), bf16-packed weights in LDS, pk_fma,
//    paired-v2f SV staging.
//  * Post-R14 variants all measured worse: conflict-fix+2-node (218),
//    skip-in-prep (283), serial split (233), 36KB fusion (226), 20KB
//    fusion (221). Locking in the champion.
//
// ws layout (float units):
//   sv1[N*64] | SVb[N*128] | recb[E*8] | cnt[N] | rs[N] | bsum[64] | boff[64]
// ---------------------------------------------------------------------------

typedef float  v2f __attribute__((ext_vector_type(2)));
typedef float  v4f __attribute__((ext_vector_type(4)));

__device__ __forceinline__ unsigned short f2bf(float x) {
    unsigned u = __float_as_uint(x);
    u += 0x7FFFu + ((u >> 16) & 1u);   // RNE
    return (unsigned short)(u >> 16);
}
__device__ __forceinline__ float bf2f(unsigned short h) {
    return __uint_as_float(((unsigned)h) << 16);
}
__device__ __forceinline__ unsigned pack_bf(float lo, float hi) {
    unsigned ul = __float_as_uint(lo);
    ul = (ul + (0x7FFFu + ((ul >> 16) & 1u))) >> 16;
    unsigned uh = __float_as_uint(hi);
    uh = (uh + (0x7FFFu + ((uh >> 16) & 1u))) & 0xFFFF0000u;
    return ul | uh;
}
__device__ __forceinline__ float bf_lo(unsigned p) { return __uint_as_float(p << 16); }
__device__ __forceinline__ float bf_hi(unsigned p) { return __uint_as_float(p & 0xFFFF0000u); }

__global__ __launch_bounds__(256) void node_prep(
    const float* __restrict__ nf, const float* __restrict__ W1_s,
    const float* __restrict__ W1_v, const int* __restrict__ eidx,
    int* __restrict__ cnt, ushort* __restrict__ sv1, int N, int E)
{
    __shared__ float w1s[1024];
    __shared__ float w1v[1024];
    __shared__ float nrow[8][128];

    // folded histogram of dst
    for (long long e = (long long)blockIdx.x * 256 + threadIdx.x; e < E;
         e += (long long)gridDim.x * 256)
        atomicAdd(cnt + eidx[(int)e], 1);

    int g = threadIdx.x >> 5;
    int w = threadIdx.x & 31;
    int n = blockIdx.x * 8 + g;

    for (int i = threadIdx.x; i < 1024; i += 256) {
        w1s[i] = W1_s[i];
        w1v[i] = W1_v[i];
    }
    if (n < N) {
        float4 q = *(const float4*)(nf + (size_t)n * 128 + w * 4);
        *(float4*)&nrow[g][w * 4] = q;
    }
    __syncthreads();
    if (n >= N) return;

    const float l1 = 0.17677669529663687f; // 1/sqrt(32)
    const float* r = nrow[g];
    float ss = 0.f, vx = 0.f, vy = 0.f, vz = 0.f;
#pragma unroll 8
    for (int u = 0; u < 32; ++u) {
        float ws = w1s[u * 32 + w];
        float wv = w1v[u * 32 + w];
        ss += r[u] * ws;
        vx += r[32 + u * 3 + 0] * wv;
        vy += r[32 + u * 3 + 1] * wv;
        vz += r[32 + u * 3 + 2] * wv;
    }
    ushort4 o;
    o.x = f2bf(ss * l1); o.y = f2bf(vx * l1);
    o.z = f2bf(vy * l1); o.w = f2bf(vz * l1);
    *(ushort4*)(sv1 + (size_t)n * 128 + w * 4) = o;
}

// ---------------- CSR build ----------------

__global__ __launch_bounds__(1024) void scan_a(
    const int* __restrict__ cnt, int* __restrict__ rs,
    int* __restrict__ bsum, int N)
{
    int i = blockIdx.x * 1024 + threadIdx.x;
    int lane = threadIdx.x & 63;
    int wid = threadIdx.x >> 6;
    int v = (i < N) ? cnt[i] : 0;
    int incl = v;
#pragma unroll
    for (int d = 1; d < 64; d <<= 1) {
        int t = __shfl_up(incl, d);
        if (lane >= d) incl += t;
    }
    __shared__ int wtot[16];
    __shared__ int woff[16];
    if (lane == 63) wtot[wid] = incl;
    __syncthreads();
    if (wid == 0) {
        int t = (lane < 16) ? wtot[lane] : 0;
        int s = t;
#pragma unroll
        for (int d = 1; d < 16; d <<= 1) {
            int q = __shfl_up(s, d);
            if (lane >= d) s += q;
        }
        if (lane < 16) woff[lane] = s - t;
        if (lane == 15) bsum[blockIdx.x] = s;
    }
    __syncthreads();
    if (i < N) rs[i] = woff[wid] + incl - v;   // block-local exclusive prefix
}

__global__ __launch_bounds__(64) void scan_b(
    const int* __restrict__ bsum, int* __restrict__ boff, int nb)
{
    int lane = threadIdx.x;
    int carry = 0;
    for (int base = 0; base < nb; base += 64) {
        int i = base + lane;
        int v = (i < nb) ? bsum[i] : 0;
        int s = v;
#pragma unroll
        for (int d = 1; d < 64; d <<= 1) {
            int t = __shfl_up(s, d);
            if (lane >= d) s += t;
        }
        if (i < nb) boff[i] = carry + s - v;
        carry += __shfl(s, 63);
    }
}

// fused scatter + edge-MLP: sequential reads; ONE 32B record per edge at the
// dst-sorted position (2 adjacent b128 stores -> 1 cache line touched).
__global__ __launch_bounds__(256) void scatter_build(
    const float* __restrict__ ea, const float* __restrict__ ee,
    const float* __restrict__ fc1, const int* __restrict__ eidx,
    int* __restrict__ rs, const int* __restrict__ boff,
    unsigned* __restrict__ recb, int E)
{
    int e = blockIdx.x * 256 + threadIdx.x;
    if (e >= E) return;
    const float rs8 = 0.35355339059327373f;   // 1/sqrt(8)

    int d = eidx[e];
    int src = eidx[E + e];
    int p = atomicAdd(rs + d, 1) + boff[d >> 10];

    const float* eep = ee + (size_t)e * 8;
    v4f e0 = *(const v4f*)eep;
    v4f e1 = *(const v4f*)(eep + 4);
    float ev[8] = {e0.x, e0.y, e0.z, e0.w, e1.x, e1.y, e1.z, e1.w};
    float hh[8];
#pragma unroll
    for (int k = 0; k < 8; ++k) {
        float t = 0.f;
#pragma unroll
        for (int i = 0; i < 8; ++i) t += ev[i] * fc1[i * 8 + k];
        t *= rs8;
        hh[k] = t * __builtin_amdgcn_rcpf(1.f + __expf(-t)) * rs8; // silu, rs8 folded
    }
    uint4 hp;
    hp.x = pack_bf(hh[0], hh[1]);
    hp.y = pack_bf(hh[2], hh[3]);
    hp.z = pack_bf(hh[4], hh[5]);
    hp.w = pack_bf(hh[6], hh[7]);
    v4f a = *(const v4f*)(ea + (size_t)e * 4);
    uint4 t2;
    t2.x = pack_bf(a.x, a.y);
    t2.y = pack_bf(a.z, a.w);
    t2.z = (unsigned)src;
    t2.w = 0u;
    unsigned* rp = recb + (size_t)p * 8;
    *(uint4*)rp       = hp;
    *(uint4*)(rp + 4) = t2;
}

// ---------------- per-node reduction (no atomics, 1 wave = 1 node) --------

__global__ __launch_bounds__(64) void reduce_kernel(
    const float* __restrict__ fc2, const ushort* __restrict__ sv1,
    const unsigned* __restrict__ recb, const int* __restrict__ rs_end,
    const int* __restrict__ boff, const int* __restrict__ cnt,
    ushort* __restrict__ SVb, int N)
{
    __shared__ float rec[64][20];   // 5.1 KB -> wave-granular scheduling

    int l = threadIdx.x;
    int h = l >> 5;
    int u = l & 31;
    int n = blockIdx.x;

    const float inv_sqrt3 = 0.5773502691896258f;

    v2f f01[8], f23[8];
#pragma unroll
    for (int k = 0; k < 8; ++k) {
        f01[k].x = fc2[k * 128 + u];
        f01[k].y = fc2[k * 128 + 32 + u];
        f23[k].x = fc2[k * 128 + 64 + u];
        f23[k].y = fc2[k * 128 + 96 + u];
    }

    int count = cnt[n];
    int start = rs_end[n] + boff[n >> 10] - count;

    float aS0 = 0.f, aS1 = 0.f;
    float aV0x = 0.f, aV0y = 0.f, aV0z = 0.f;
    float aV1x = 0.f, aV1y = 0.f, aV1z = 0.f;

    for (int j0 = 0; j0 < count; j0 += 64) {
        int nk = count - j0; if (nk > 64) nk = 64;
        // phase 1: coalesced 32B record load + unpack (MLP precomputed)
        if (l < nk) {
            const unsigned* rp = recb + (size_t)(start + j0 + l) * 8;
            uint4 hq = *(const uint4*)rp;
            uint4 aq = *(const uint4*)(rp + 4);
            float* rr = &rec[l][0];
            *(v4f*)rr       = (v4f){bf_lo(hq.x), bf_hi(hq.x), bf_lo(hq.y), bf_hi(hq.y)};
            *(v4f*)(rr + 4) = (v4f){bf_lo(hq.z), bf_hi(hq.z), bf_lo(hq.w), bf_hi(hq.w)};
            *(v4f*)(rr + 8) = (v4f){bf_lo(aq.x), bf_hi(aq.x), bf_lo(aq.y), bf_hi(aq.y)};
            rr[12] = __uint_as_float(aq.z);
        }
        // phase 2: 2 edges/iteration (h picks the edge), branchless 1-deep
        // sv1-row prefetch.
        int pairs = (nk + 1) >> 1;
        int last = nk - 1;
        int s0 = __float_as_int(rec[h <= last ? h : last][12]);
        ushort4 q = *(const ushort4*)(sv1 + (size_t)s0 * 128 + u * 4);
        for (int jj = 0; jj < pairs; ++jj) {
            int slot = jj * 2 + h;
            int nslot = slot + 2 <= last ? slot + 2 : last;
            int sN = __float_as_int(rec[nslot][12]);
            ushort4 qn = *(const ushort4*)(sv1 + (size_t)sN * 128 + u * 4);

            float msk = (slot <= last) ? 1.f : 0.f;
            int slotc = slot <= last ? slot : last;
            const float* rr = &rec[slotc][0];
            v4f H0 = *(const v4f*)rr;
            v4f H1 = *(const v4f*)(rr + 4);
            v4f A  = *(const v4f*)(rr + 8);
            float ss = bf2f(q.x) * msk;
            float vx = bf2f(q.y), vy = bf2f(q.z), vz = bf2f(q.w);

            v2f w01 = H0.x * f01[0] + H0.y * f01[1] + H0.z * f01[2] + H0.w * f01[3]
                    + H1.x * f01[4] + H1.y * f01[5] + H1.z * f01[6] + H1.w * f01[7];
            v2f w23 = H0.x * f23[0] + H0.y * f23[1] + H0.z * f23[2] + H0.w * f23[3]
                    + H1.x * f23[4] + H1.y * f23[5] + H1.z * f23[6] + H1.w * f23[7];

            float dv = (vx * A.y + vy * A.z + vz * A.w) * msk;
            aS0 += w01.x * (ss * A.x);
            aS1 += w23.y * dv;
            float c1 = w01.y * ss;
            aV0x += c1 * A.y; aV0y += c1 * A.z; aV0z += c1 * A.w;
            float c2 = w23.x * A.x * msk;
            aV1x += c2 * vx; aV1y += c2 * vy; aV1z += c2 * vz;
            q = qn;
        }
    }

    aS0  += __shfl_xor(aS0, 32);
    aS1  += __shfl_xor(aS1, 32);
    aV0x += __shfl_xor(aV0x, 32);
    aV0y += __shfl_xor(aV0y, 32);
    aV0z += __shfl_xor(aV0z, 32);
    aV1x += __shfl_xor(aV1x, 32);
    aV1y += __shfl_xor(aV1y, 32);
    aV1z += __shfl_xor(aV1z, 32);

    if (h == 0) {
        // SVb[n][u] packed: {S0,S1'} {V0x,V0y} {V0z,V1x} {V1y,V1z}
        uint4 o;
        o.x = pack_bf(aS0, aS1 * inv_sqrt3);
        o.y = pack_bf(aV0x, aV0y);
        o.z = pack_bf(aV0z, aV1x);
        o.w = pack_bf(aV1y, aV1z);
        *(uint4*)(SVb + (size_t)n * 256 + u * 8) = o;
    }
}

// ---------------- fused final: pk_fma, paired-v2f SV, bf16 weights --------

__global__ __launch_bounds__(256) void node_final(
    const ushort* __restrict__ SVb, const float* __restrict__ W2_s,
    const float* __restrict__ W2_v, const float* __restrict__ nf,
    const float* __restrict__ nattr, const float* __restrict__ Wsc_s,
    const float* __restrict__ Wsc_v, float* __restrict__ out, int N)
{
    // wqb[i]  = {pack(W2s[u][w],W2v[u][w]), pack(W2s[u+32][w],W2v[u+32][w])}
    // wsvb[i] = {pack(ws_a,wv_a)} a=0..3, ws_a=Wsc_s[u][a][w]
    __shared__ uint2 wqb[1024];       // 8 KB
    __shared__ uint4 wsvb[1024];      // 16 KB
    __shared__ v2f   svtp[8][32][4];  // 8 KB  pairs P0..P3 per u
    __shared__ float nrow[8][128];    // 4 KB  -> 36 KB total, 4 blk/CU

    int g = threadIdx.x >> 5;
    int w = threadIdx.x & 31;

    for (int i = threadIdx.x; i < 1024; i += 256) {  // i = u*32+w
        int uu = i >> 5, ww = i & 31;
        wqb[i] = (uint2){pack_bf(W2_s[i], W2_v[i]),
                         pack_bf(W2_s[i + 1024], W2_v[i + 1024])};
        const float* ps = Wsc_s + (size_t)uu * 128 + ww;
        const float* pv = Wsc_v + (size_t)uu * 128 + ww;
        wsvb[i] = (uint4){pack_bf(ps[0],  pv[0]),
                          pack_bf(ps[32], pv[32]),
                          pack_bf(ps[64], pv[64]),
                          pack_bf(ps[96], pv[96])};
    }
    __syncthreads();

    const float l2 = 0.125f;                    // 1/sqrt(64)
    const float sc_norm = 0.08838834764831843f; // 1/sqrt(128)

    for (int t = 0; t < 4; ++t) {
        int n = blockIdx.x * 32 + g * 4 + t;
        if (n >= N) continue;
        // stage SV row as the 4 pairs the pk_fma loop needs:
        uint4 p = *(const uint4*)(SVb + (size_t)n * 256 + w * 8);
        svtp[g][w][0] = (v2f){bf_lo(p.x), bf_lo(p.z)};   // {S0 , V0z}
        svtp[g][w][1] = (v2f){bf_hi(p.x), bf_hi(p.w)};   // {S1', V1z}
        svtp[g][w][2] = (v2f){bf_lo(p.y), bf_hi(p.y)};   // {V0x, V0y}
        svtp[g][w][3] = (v2f){bf_hi(p.z), bf_lo(p.w)};   // {V1x, V1y}
        float4 q = *(const float4*)(nf + (size_t)n * 128 + w * 4);
        *(float4*)&nrow[g][w * 4] = q;
        float at0 = nattr[(size_t)n * 4 + 0];
        float at1 = nattr[(size_t)n * 4 + 1];
        float at2 = nattr[(size_t)n * 4 + 2];
        float at3 = nattr[(size_t)n * 4 + 3];
        // same-wave LDS visibility (32-lane group within one wave)

        v2f sa_va2 = (v2f){0.f, 0.f};
        v2f va01   = (v2f){0.f, 0.f};
        v2f scv01  = (v2f){0.f, 0.f};
        float scs = 0.f, scv2 = 0.f;
#pragma unroll
        for (int u = 0; u < 32; ++u) {
            int idx = u * 32 + w;
            uint2 qw = wqb[idx];
            float w2s_a = bf_lo(qw.x), w2v_a = bf_hi(qw.x);
            float w2s_b = bf_lo(qw.y), w2v_b = bf_hi(qw.y);
            v2f Q0 = svtp[g][u][0], Q1 = svtp[g][u][1];
            v2f Q2 = svtp[g][u][2], Q3 = svtp[g][u][3];
            sa_va2 += Q0 * (v2f){w2s_a, w2v_a};
            sa_va2 += Q1 * (v2f){w2s_b, w2v_b};
            va01   += Q2 * (v2f){w2v_a, w2v_a};
            va01   += Q3 * (v2f){w2v_b, w2v_b};
            uint4 wv = wsvb[idx];
            v2f csv = at0 * (v2f){bf_lo(wv.x), bf_hi(wv.x)}
                    + at1 * (v2f){bf_lo(wv.y), bf_hi(wv.y)}
                    + at2 * (v2f){bf_lo(wv.z), bf_hi(wv.z)}
                    + at3 * (v2f){bf_lo(wv.w), bf_hi(wv.w)};  // {cs, cv}
            float su = nrow[g][u];
            float vx = nrow[g][32 + u * 3 + 0];
            float vy = nrow[g][32 + u * 3 + 1];
            float vz = nrow[g][32 + u * 3 + 2];
            scs   += su * csv.x;
            scv01 += (v2f){vx, vy} * (v2f){csv.y, csv.y};
            scv2  += vz * csv.y;
        }
        float* orow = out + (size_t)n * 128;
        orow[w]              = sa_va2.x * l2 + scs     * sc_norm;
        orow[32 + w * 3 + 0] = va01.x   * l2 + scv01.x * sc_norm;
        orow[32 + w * 3 + 1] = va01.y   * l2 + scv01.y * sc_norm;
        orow[32 + w * 3 + 2] = sa_va2.y * l2 + scv2    * sc_norm;
    }
}

// ---------------- fallback (atomic path, float SV) ----------------

__global__ __launch_bounds__(256) void edge_kernel(
    const float* __restrict__ ea, const float* __restrict__ ee,
    const float* __restrict__ fc1, const float* __restrict__ fc2,
    const ushort* __restrict__ sv1, const int* __restrict__ eidx,
    float* __restrict__ SV, int E)
{
    long long tid = (long long)blockIdx.x * 256 + threadIdx.x;
    int e = (int)(tid >> 5);
    int u = (int)(tid & 31);
    if (e >= E) return;
    const float rs8 = 0.35355339059327373f;
    const float inv_sqrt3 = 0.5773502691896258f;
    float ev[8];
#pragma unroll
    for (int i = 0; i < 8; ++i) ev[i] = ee[(size_t)e * 8 + i];
    float h[8];
#pragma unroll
    for (int k = 0; k < 8; ++k) {
        float t = 0.f;
#pragma unroll
        for (int i = 0; i < 8; ++i) t += ev[i] * fc1[i * 8 + k];
        t *= rs8;
        h[k] = t / (1.f + expf(-t));
    }
    float w0 = 0.f, w1 = 0.f, w2 = 0.f, w3 = 0.f;
#pragma unroll
    for (int k = 0; k < 8; ++k) {
        const float* f2 = fc2 + k * 128;
        float hk = h[k];
        w0 += hk * f2[u];
        w1 += hk * f2[32 + u];
        w2 += hk * f2[64 + u];
        w3 += hk * f2[96 + u];
    }
    w0 *= rs8; w1 *= rs8; w2 *= rs8; w3 *= rs8;
    int dst = eidx[e];
    int src = eidx[E + e];
    float a0 = ea[(size_t)e * 4 + 0];
    float ax = ea[(size_t)e * 4 + 1];
    float ay = ea[(size_t)e * 4 + 2];
    float az = ea[(size_t)e * 4 + 3];
    ushort4 q = *(const ushort4*)(sv1 + (size_t)src * 128 + u * 4);
    float ss = bf2f(q.x), vx = bf2f(q.y), vy = bf2f(q.z), vz = bf2f(q.w);
    float dv = vx * ax + vy * ay + vz * az;
    float* o = SV + (size_t)dst * 256 + u * 8;
    atomicAdd(o + 0, w0 * ss * a0);
    atomicAdd(o + 1, w3 * dv * inv_sqrt3);
    float c1 = w1 * ss;
    atomicAdd(o + 2, c1 * ax);
    atomicAdd(o + 3, c1 * ay);
    atomicAdd(o + 4, c1 * az);
    float c2 = w2 * a0;
    atomicAdd(o + 5, c2 * vx);
    atomicAdd(o + 6, c2 * vy);
    atomicAdd(o + 7, c2 * vz);
}

__global__ __launch_bounds__(256) void node_final_f32(
    const float* __restrict__ SV, const float* __restrict__ W2_s,
    const float* __restrict__ W2_v, const float* __restrict__ nf,
    const float* __restrict__ nattr, const float* __restrict__ Wsc_s,
    const float* __restrict__ Wsc_v, float* __restrict__ out, int N)
{
    __shared__ float wq[4096];
    __shared__ float wsp[4096];
    __shared__ float wvp[4096];
    __shared__ float svt[8][8][32];
    __shared__ float nrow[8][128];

    int g = threadIdx.x >> 5;
    int w = threadIdx.x & 31;

    for (int i = threadIdx.x; i < 1024; i += 256) {
        int uu = i >> 5, ww = i & 31;
        *(float4*)&wq[i * 4] = make_float4(W2_s[i], W2_s[i + 1024],
                                           W2_v[i], W2_v[i + 1024]);
        const float* ps = Wsc_s + (size_t)uu * 128 + ww;
        const float* pv = Wsc_v + (size_t)uu * 128 + ww;
        *(float4*)&wsp[i * 4] = make_float4(ps[0], ps[32], ps[64], ps[96]);
        *(float4*)&wvp[i * 4] = make_float4(pv[0], pv[32], pv[64], pv[96]);
    }
    __syncthreads();

    const float l2 = 0.125f;
    const float sc_norm = 0.08838834764831843f;

    for (int t = 0; t < 4; ++t) {
        int n = blockIdx.x * 32 + g * 4 + t;
        if (n >= N) continue;
        const float* svp = SV + (size_t)n * 256 + w * 8;
        float4 p0 = *(const float4*)svp;
        float4 p1 = *(const float4*)(svp + 4);
        svt[g][0][w] = p0.x; svt[g][1][w] = p0.y;
        svt[g][2][w] = p0.z; svt[g][3][w] = p0.w;
        svt[g][4][w] = p1.x; svt[g][5][w] = p1.y;
        svt[g][6][w] = p1.z; svt[g][7][w] = p1.w;
        float4 q = *(const float4*)(nf + (size_t)n * 128 + w * 4);
        *(float4*)&nrow[g][w * 4] = q;
        float at0 = nattr[(size_t)n * 4 + 0];
        float at1 = nattr[(size_t)n * 4 + 1];
        float at2 = nattr[(size_t)n * 4 + 2];
        float at3 = nattr[(size_t)n * 4 + 3];

        float sa = 0.f, va0 = 0.f, va1 = 0.f, va2 = 0.f;
        float scs = 0.f, scv0 = 0.f, scv1 = 0.f, scv2 = 0.f;
#pragma unroll
        for (int u = 0; u < 32; ++u) {
            float4 qw = *(const float4*)&wq[(u * 32 + w) * 4];
            sa  += svt[g][0][u] * qw.x + svt[g][1][u] * qw.y;
            va0 += svt[g][2][u] * qw.z + svt[g][5][u] * qw.w;
            va1 += svt[g][3][u] * qw.z + svt[g][6][u] * qw.w;
            va2 += svt[g][4][u] * qw.z + svt[g][7][u] * qw.w;
            float4 ps = *(const float4*)&wsp[(u * 32 + w) * 4];
            float4 pv = *(const float4*)&wvp[(u * 32 + w) * 4];
            float cs = at0 * ps.x + at1 * ps.y + at2 * ps.z + at3 * ps.w;
            float cv = at0 * pv.x + at1 * pv.y + at2 * pv.z + at3 * pv.w;
            scs  += nrow[g][u] * cs;
            scv0 += nrow[g][32 + u * 3 + 0] * cv;
            scv1 += nrow[g][32 + u * 3 + 1] * cv;
            scv2 += nrow[g][32 + u * 3 + 2] * cv;
        }
        float* orow = out + (size_t)n * 128;
        orow[w] = sa * l2 + scs * sc_norm;
        orow[32 + w * 3 + 0] = va0 * l2 + scv0 * sc_norm;
        orow[32 + w * 3 + 1] = va1 * l2 + scv1 * sc_norm;
        orow[32 + w * 3 + 2] = va2 * l2 + scv2 * sc_norm;
    }
}

extern "C" void kernel_launch(void* const* d_in, const int* in_sizes, int n_in,
                              void* d_out, int out_size, void* d_ws, size_t ws_size,
                              hipStream_t stream) {
    const float* nf    = (const float*)d_in[0];
    const float* nattr = (const float*)d_in[1];
    const float* ea    = (const float*)d_in[2];
    const float* ee    = (const float*)d_in[3];
    const float* W1_s  = (const float*)d_in[4];
    const float* W1_v  = (const float*)d_in[5];
    const float* fc1   = (const float*)d_in[6];
    const float* fc2   = (const float*)d_in[7];
    const float* W2_s  = (const float*)d_in[8];
    const float* W2_v  = (const float*)d_in[9];
    const float* Wsc_s = (const float*)d_in[10];
    const float* Wsc_v = (const float*)d_in[11];
    const int*   eidx  = (const int*)d_in[12];

    int N = in_sizes[0] / 128;
    int E = in_sizes[12] / 2;

    float* ws = (float*)d_ws;
    // main-path layout (float units)
    ushort* sv1 = (ushort*)ws;                         // N*128 ushorts (N*64 f)
    ushort* SVb = (ushort*)(ws + (size_t)N * 64);      // N*256 ushorts (N*128 f)
    unsigned* recb = (unsigned*)(ws + (size_t)N * 192); // E*8 uints
    int* cnt  = (int*)(ws + (size_t)N * 192 + (size_t)E * 8); // N
    int* rs   = cnt + N;                               // N
    int* bsum = rs + N;                                // 64
    int* boff = bsum + 64;                             // 64

    size_t needed = ((size_t)N * 194 + (size_t)E * 8 + 128) * 4;

    int nb_node = (N + 7) / 8;
    int nbE = (E + 255) / 256;
    int nb_final = (N + 31) / 32;

    if (ws_size >= needed) {
        hipMemsetAsync(cnt, 0, (size_t)N * sizeof(int), stream);
        node_prep<<<nb_node, 256, 0, stream>>>(nf, W1_s, W1_v, eidx, cnt, sv1, N, E);
        int nbS = (N + 1023) / 1024;
        scan_a<<<nbS, 1024, 0, stream>>>(cnt, rs, bsum, N);
        scan_b<<<1, 64, 0, stream>>>(bsum, boff, nbS);
        scatter_build<<<nbE, 256, 0, stream>>>(ea, ee, fc1, eidx, rs, boff,
                                               recb, E);
        reduce_kernel<<<N, 64, 0, stream>>>(fc2, sv1, recb, rs, boff, cnt,
                                            SVb, N);
        node_final<<<nb_final, 256, 0, stream>>>(SVb, W2_s, W2_v, nf, nattr,
                                                 Wsc_s, Wsc_v, (float*)d_out, N);
    } else {
        // fallback: atomic path with float SV
        float* SVf = ws + (size_t)N * 64;           // N*256 floats
        int* cnt_f = (int*)(SVf + (size_t)N * 256); // N
        hipMemsetAsync(SVf, 0, (size_t)N * 256 * sizeof(float), stream);
        node_prep<<<nb_node, 256, 0, stream>>>(nf, W1_s, W1_v, eidx, cnt_f, sv1, N, E);
        long long tot = (long long)E * 32;
        int nb_edge = (int)((tot + 255) / 256);
        edge_kernel<<<nb_edge, 256, 0, stream>>>(ea, ee, fc1, fc2, sv1, eidx, SVf, E);
        node_final_f32<<<nb_final, 256, 0, stream>>>(SVf, W2_s, W2_v, nf, nattr,
                                                     Wsc_s, Wsc_v, (float*)d_out, N);
    }
}